// Round 3
// baseline (1283.156 us; speedup 1.0000x reference)
//
#include <hip/hip_runtime.h>

#define N_NODES 131072
#define E_EDGES 524288
#define B_GR    2048
#define H_DIM   128
#define NF_DIM  30
#define GF_DIM  4415
#define GF_PAD  4416            // 138*32
#define BN_SCALE 0.9999950000374997f   // 1/sqrt(1+1e-5)

typedef __bf16 bf16x8 __attribute__((ext_vector_type(8)));
typedef float  f32x4  __attribute__((ext_vector_type(4)));
typedef unsigned int uint32;

__device__ __forceinline__ void split2(float x, __bf16& hi, __bf16& lo){
    hi = (__bf16)x;
    lo = (__bf16)(x - (float)hi);
}
__device__ __forceinline__ uint32 bfbits(float x){
    __bf16 h = (__bf16)x;
    return (uint32)__builtin_bit_cast(unsigned short, h);
}

// ---------------- graph prep ----------------

__global__ void k_zero_int(int* __restrict__ p, int n){
    int i = blockIdx.x*256 + threadIdx.x;
    if(i < n) p[i] = 0;
}

__global__ void k_count(const int* __restrict__ dst, int* __restrict__ counts){
    int e = blockIdx.x*256 + threadIdx.x;
    if(e < E_EDGES) atomicAdd(&counts[dst[e]], 1);
}

__global__ void k_scan1(int* __restrict__ counts, int* __restrict__ bsums){
    __shared__ int s[1024];
    int t = threadIdx.x;
    int gi = blockIdx.x*1024 + t;
    int v = counts[gi];
    s[t] = v; __syncthreads();
    for(int off=1; off<1024; off<<=1){
        int x = (t>=off) ? s[t-off] : 0;
        __syncthreads();
        s[t] += x;
        __syncthreads();
    }
    counts[gi] = s[t] - v;
    if(t == 1023) bsums[blockIdx.x] = s[t];
}

__global__ void k_scan2(int* __restrict__ bsums){
    __shared__ int s[128];
    int t = threadIdx.x;
    int v = bsums[t]; s[t] = v; __syncthreads();
    for(int off=1; off<128; off<<=1){
        int x = (t>=off) ? s[t-off] : 0;
        __syncthreads();
        s[t] += x;
        __syncthreads();
    }
    bsums[t] = s[t] - v;
}

__global__ void k_scan3(const int* __restrict__ counts, const int* __restrict__ bsums,
                        int* __restrict__ rowptr){
    int i = blockIdx.x*1024 + threadIdx.x;
    rowptr[i] = counts[i] + bsums[blockIdx.x];
    if(i == 0) rowptr[N_NODES] = E_EDGES;
}

__global__ void k_dinv_cursor(const int* __restrict__ rowptr, float* __restrict__ dinv,
                              int* __restrict__ cursor){
    int n = blockIdx.x*256 + threadIdx.x;
    if(n < N_NODES){
        int a = rowptr[n], b = rowptr[n+1];
        dinv[n] = rsqrtf((float)(b - a) + 1.0f);
        cursor[n] = a;
    }
}

__global__ void k_fill(const int* __restrict__ src, const int* __restrict__ dst,
                       int* __restrict__ cursor, int* __restrict__ csr){
    int e = blockIdx.x*256 + threadIdx.x;
    if(e < E_EDGES){
        int p = atomicAdd(&cursor[dst[e]], 1);
        csr[p] = src[e];
    }
}

// ---------------- split-conversion kernels ----------------

__global__ void k_split_x(const float* __restrict__ x, __bf16* __restrict__ xh,
                          __bf16* __restrict__ xl){
    int idx = blockIdx.x*256 + threadIdx.x;          // N*32
    int n = idx >> 5, k = idx & 31;
    float v = (k < NF_DIM) ? x[n*NF_DIM + k] : 0.f;
    split2(v, xh[idx], xl[idx]);
}

__global__ void k_split_wemb(const float* __restrict__ W, __bf16* __restrict__ th,
                             __bf16* __restrict__ tl){
    int idx = blockIdx.x*256 + threadIdx.x;          // 128*32  (c-major, k padded)
    int c = idx >> 5, k = idx & 31;
    float v = (k < NF_DIM) ? W[k*H_DIM + c] : 0.f;
    split2(v, th[idx], tl[idx]);
}

__global__ void k_split_wg(const float* __restrict__ Wg, __bf16* __restrict__ th,
                           __bf16* __restrict__ tl){
    int idx = blockIdx.x*256 + threadIdx.x;          // 3*128*128
    int l = idx >> 14, i = idx & 16383;
    int k = i >> 7, c = i & 127;
    float v = Wg[idx];
    int o = (l << 14) + (c << 7) + k;                // transposed: [l][c][k]
    split2(v, th[o], tl[o]);
}

__global__ void k_split_gf(const float* __restrict__ gf, __bf16* __restrict__ ah,
                           __bf16* __restrict__ al){
    unsigned idx = blockIdx.x*256 + threadIdx.x;     // 2048*4416
    unsigned r = idx / GF_PAD, k = idx - r*GF_PAD;
    float v = (k < GF_DIM) ? gf[(size_t)r*GF_DIM + k] : 0.f;
    split2(v, ah[idx], al[idx]);
}

__global__ void k_split_wge1(const float* __restrict__ W, __bf16* __restrict__ th,
                             __bf16* __restrict__ tl){
    unsigned idx = blockIdx.x*256 + threadIdx.x;     // 256*4416 (c-major, k padded)
    unsigned c = idx / GF_PAD, k = idx - c*GF_PAD;
    float v = (k < GF_DIM) ? W[(size_t)k*256 + c] : 0.f;
    split2(v, th[idx], tl[idx]);
}

// ---------------- embedding via MFMA:  relu(x @ W_emb + b) -> (Hh,Hl) ----------------

__global__ __launch_bounds__(256)
void k_emb_mfma(const __bf16* __restrict__ xh, const __bf16* __restrict__ xl,
                const __bf16* __restrict__ wth, const __bf16* __restrict__ wtl,
                const float* __restrict__ bias, __bf16* __restrict__ Hh,
                __bf16* __restrict__ Hl){
    int wave = threadIdx.x >> 6, lane = threadIdx.x & 63;
    int lr = lane & 15, lq = lane >> 4;
    int rbase = blockIdx.x*128 + wave*32;
    const f32x4 zero4 = {0.f,0.f,0.f,0.f};
    bf16x8 A0h = *(const bf16x8*)(xh + (size_t)(rbase + lr)*32 + lq*8);
    bf16x8 A0l = *(const bf16x8*)(xl + (size_t)(rbase + lr)*32 + lq*8);
    bf16x8 A1h = *(const bf16x8*)(xh + (size_t)(rbase + 16 + lr)*32 + lq*8);
    bf16x8 A1l = *(const bf16x8*)(xl + (size_t)(rbase + 16 + lr)*32 + lq*8);
    #pragma unroll
    for(int ct=0;ct<8;ct++){
        int col = ct*16 + lr;
        bf16x8 Bh = *(const bf16x8*)(wth + col*32 + lq*8);
        bf16x8 Bl = *(const bf16x8*)(wtl + col*32 + lq*8);
        f32x4 a0 = zero4, a1 = zero4;
        a0 = __builtin_amdgcn_mfma_f32_16x16x32_bf16(A0h, Bh, a0, 0,0,0);
        a0 = __builtin_amdgcn_mfma_f32_16x16x32_bf16(A0l, Bh, a0, 0,0,0);
        a0 = __builtin_amdgcn_mfma_f32_16x16x32_bf16(A0h, Bl, a0, 0,0,0);
        a1 = __builtin_amdgcn_mfma_f32_16x16x32_bf16(A1h, Bh, a1, 0,0,0);
        a1 = __builtin_amdgcn_mfma_f32_16x16x32_bf16(A1l, Bh, a1, 0,0,0);
        a1 = __builtin_amdgcn_mfma_f32_16x16x32_bf16(A1h, Bl, a1, 0,0,0);
        float bb = bias[col];
        #pragma unroll
        for(int r=0;r<4;r++){
            size_t i0 = (size_t)(rbase + lq*4 + r)*H_DIM + col;
            size_t i1 = (size_t)(rbase + 16 + lq*4 + r)*H_DIM + col;
            float v0 = fmaxf(a0[r] + bb, 0.f);
            float v1 = fmaxf(a1[r] + bb, 0.f);
            split2(v0, Hh[i0], Hl[i0]);
            split2(v1, Hh[i1], Hl[i1]);
        }
    }
}

// ---------------- normalized aggregation on H (before matmul) ----------------
// agg[n] = dinv[n] * ( (Hh+Hl)[n]*dinv[n] + sum_s Hh[s]*dinv[s] )
// neighbor gather reads 2-byte Hh only; 4-deep pipelined; output split to (Ah,Al).

__global__ __launch_bounds__(256)
void k_agg(const __bf16* __restrict__ Hh, const __bf16* __restrict__ Hl,
           const float* __restrict__ dinv, const int* __restrict__ rowptr,
           const int* __restrict__ csr, uint32* __restrict__ Ah2,
           uint32* __restrict__ Al2){
    int wave = threadIdx.x >> 6, lane = threadIdx.x & 63;
    int n = blockIdx.x*4 + wave;
    float dn = dinv[n];
    size_t i0 = (size_t)n*64 + lane;        // uint32 units (2 bf16 per uint)
    const uint32* Hh2 = (const uint32*)Hh;
    const uint32* Hl2 = (const uint32*)Hl;
    uint32 sh = Hh2[i0], sl = Hl2[i0];
    float sx = __uint_as_float(sh<<16) + __uint_as_float(sl<<16);
    float sy = __uint_as_float(sh & 0xffff0000u) + __uint_as_float(sl & 0xffff0000u);
    float ax = sx*dn, ay = sy*dn;
    int j0 = rowptr[n], j1 = rowptr[n+1];
    int jm = j1 - 1;
    for(int j=j0; j<j1; j+=4){
        int i1 = (j+1<=jm)? j+1 : jm;
        int i2 = (j+2<=jm)? j+2 : jm;
        int i3 = (j+3<=jm)? j+3 : jm;
        int s0 = csr[j], s1 = csr[i1], s2 = csr[i2], s3 = csr[i3];
        float w0 = dinv[s0];
        float w1 = (j+1<=jm)? dinv[s1] : 0.f;
        float w2 = (j+2<=jm)? dinv[s2] : 0.f;
        float w3 = (j+3<=jm)? dinv[s3] : 0.f;
        uint32 r0 = Hh2[(size_t)s0*64 + lane];
        uint32 r1 = Hh2[(size_t)s1*64 + lane];
        uint32 r2 = Hh2[(size_t)s2*64 + lane];
        uint32 r3 = Hh2[(size_t)s3*64 + lane];
        ax = fmaf(__uint_as_float(r0<<16), w0, ax);
        ay = fmaf(__uint_as_float(r0 & 0xffff0000u), w0, ay);
        ax = fmaf(__uint_as_float(r1<<16), w1, ax);
        ay = fmaf(__uint_as_float(r1 & 0xffff0000u), w1, ay);
        ax = fmaf(__uint_as_float(r2<<16), w2, ax);
        ay = fmaf(__uint_as_float(r2 & 0xffff0000u), w2, ay);
        ax = fmaf(__uint_as_float(r3<<16), w3, ax);
        ay = fmaf(__uint_as_float(r3 & 0xffff0000u), w3, ay);
    }
    ax *= dn; ay *= dn;
    uint32 hx = bfbits(ax), hy = bfbits(ay);
    Ah2[i0] = hx | (hy<<16);
    float lx = ax - __uint_as_float(hx<<16);
    float ly = ay - __uint_as_float(hy<<16);
    Al2[i0] = bfbits(lx) | (bfbits(ly)<<16);
}

// ---------------- matmul + bias + BN + ReLU + residual -> (Hh,Hl) ----------------

__global__ __launch_bounds__(256)
void k_mm_epi(const __bf16* __restrict__ Ah, const __bf16* __restrict__ Al,
              const __bf16* __restrict__ Bth, const __bf16* __restrict__ Btl,
              const float* __restrict__ bias, const float* __restrict__ gamma,
              const float* __restrict__ beta, __bf16* __restrict__ Hh,
              __bf16* __restrict__ Hl, int residual){
    int wave = threadIdx.x >> 6, lane = threadIdx.x & 63;
    int lr = lane & 15, lq = lane >> 4;
    int rbase = blockIdx.x*128 + wave*32;
    const f32x4 zero4 = {0.f,0.f,0.f,0.f};
    size_t o0 = (size_t)(rbase + lr)*H_DIM + lq*8;
    size_t o1 = o0 + (size_t)16*H_DIM;
    bf16x8 A0h[4], A0l[4], A1h[4], A1l[4];
    #pragma unroll
    for(int ks=0;ks<4;ks++){
        A0h[ks] = *(const bf16x8*)(Ah + o0 + ks*32);
        A0l[ks] = *(const bf16x8*)(Al + o0 + ks*32);
        A1h[ks] = *(const bf16x8*)(Ah + o1 + ks*32);
        A1l[ks] = *(const bf16x8*)(Al + o1 + ks*32);
    }
    #pragma unroll
    for(int ct=0;ct<8;ct++){
        int col = ct*16 + lr;
        f32x4 a0 = zero4, a1 = zero4;
        #pragma unroll
        for(int ks=0;ks<4;ks++){
            bf16x8 Bh = *(const bf16x8*)(Bth + col*H_DIM + ks*32 + lq*8);
            bf16x8 Bl = *(const bf16x8*)(Btl + col*H_DIM + ks*32 + lq*8);
            a0 = __builtin_amdgcn_mfma_f32_16x16x32_bf16(A0h[ks], Bh, a0, 0,0,0);
            a0 = __builtin_amdgcn_mfma_f32_16x16x32_bf16(A0l[ks], Bh, a0, 0,0,0);
            a0 = __builtin_amdgcn_mfma_f32_16x16x32_bf16(A0h[ks], Bl, a0, 0,0,0);
            a1 = __builtin_amdgcn_mfma_f32_16x16x32_bf16(A1h[ks], Bh, a1, 0,0,0);
            a1 = __builtin_amdgcn_mfma_f32_16x16x32_bf16(A1l[ks], Bh, a1, 0,0,0);
            a1 = __builtin_amdgcn_mfma_f32_16x16x32_bf16(A1h[ks], Bl, a1, 0,0,0);
        }
        float bb = bias[col];
        float gs = gamma[col]*BN_SCALE;
        float bt = beta[col];
        #pragma unroll
        for(int r=0;r<4;r++){
            size_t i0 = (size_t)(rbase + lq*4 + r)*H_DIM + col;
            size_t i1 = (size_t)(rbase + 16 + lq*4 + r)*H_DIM + col;
            float v0 = fmaxf(fmaf(a0[r] + bb, gs, bt), 0.f);
            float v1 = fmaxf(fmaf(a1[r] + bb, gs, bt), 0.f);
            if(residual){
                v0 += (float)Hh[i0] + (float)Hl[i0];
                v1 += (float)Hh[i1] + (float)Hl[i1];
            }
            split2(v0, Hh[i0], Hl[i0]);
            split2(v1, Hh[i1], Hl[i1]);
        }
    }
}

// ---------------- gene GEMM via MFMA, split-K partials (no atomics) ----------------

__global__ __launch_bounds__(256)
void k_gemm_gf_mfma(const __bf16* __restrict__ Ah, const __bf16* __restrict__ Al,
                    const __bf16* __restrict__ Bth, const __bf16* __restrict__ Btl,
                    float* __restrict__ gpart){
    int rt = blockIdx.x & 31;       // 32 row tiles of 64
    int sp = blockIdx.x >> 5;       // 8 k-splits
    int ks0 = (sp*138) >> 3, ks1 = ((sp+1)*138) >> 3;
    int wave = threadIdx.x >> 6, lane = threadIdx.x & 63;
    int lr = lane & 15, lq = lane >> 4;
    int rbase = rt*64 + (wave & 1)*32;
    int cbase = (wave >> 1)*128;
    const f32x4 zero4 = {0.f,0.f,0.f,0.f};
    f32x4 acc[8][2];
    #pragma unroll
    for(int ct=0;ct<8;ct++){ acc[ct][0] = zero4; acc[ct][1] = zero4; }
    for(int ks=ks0; ks<ks1; ks++){
        int kc = ks*32;
        size_t oa0 = (size_t)(rbase + lr)*GF_PAD + kc + lq*8;
        size_t oa1 = oa0 + (size_t)16*GF_PAD;
        bf16x8 A0h = *(const bf16x8*)(Ah + oa0);
        bf16x8 A0l = *(const bf16x8*)(Al + oa0);
        bf16x8 A1h = *(const bf16x8*)(Ah + oa1);
        bf16x8 A1l = *(const bf16x8*)(Al + oa1);
        #pragma unroll
        for(int ct=0;ct<8;ct++){
            size_t bo = (size_t)(cbase + ct*16 + lr)*GF_PAD + kc + lq*8;
            bf16x8 Bh = *(const bf16x8*)(Bth + bo);
            bf16x8 Bl = *(const bf16x8*)(Btl + bo);
            acc[ct][0] = __builtin_amdgcn_mfma_f32_16x16x32_bf16(A0h, Bh, acc[ct][0], 0,0,0);
            acc[ct][0] = __builtin_amdgcn_mfma_f32_16x16x32_bf16(A0l, Bh, acc[ct][0], 0,0,0);
            acc[ct][0] = __builtin_amdgcn_mfma_f32_16x16x32_bf16(A0h, Bl, acc[ct][0], 0,0,0);
            acc[ct][1] = __builtin_amdgcn_mfma_f32_16x16x32_bf16(A1h, Bh, acc[ct][1], 0,0,0);
            acc[ct][1] = __builtin_amdgcn_mfma_f32_16x16x32_bf16(A1l, Bh, acc[ct][1], 0,0,0);
            acc[ct][1] = __builtin_amdgcn_mfma_f32_16x16x32_bf16(A1h, Bl, acc[ct][1], 0,0,0);
        }
    }
    float* po = gpart + (size_t)sp*(B_GR*256);
    #pragma unroll
    for(int ct=0;ct<8;ct++)
        #pragma unroll
        for(int s=0;s<2;s++)
            #pragma unroll
            for(int r=0;r<4;r++)
                po[(size_t)(rbase + s*16 + lq*4 + r)*256 + cbase + ct*16 + lr] = acc[ct][s][r];
}

__global__ void k_gene_reduce(const float* __restrict__ gpart, const float* __restrict__ bias,
                              const float* __restrict__ gamma, const float* __restrict__ beta,
                              float* __restrict__ g1){
    int i = blockIdx.x*256 + threadIdx.x;   // B*256
    int c = i & 255;
    float v = bias[c];
    #pragma unroll
    for(int sp=0;sp<8;sp++) v += gpart[(size_t)sp*(B_GR*256) + i];
    v = fmaf(v, gamma[c]*BN_SCALE, beta[c]);
    g1[i] = fmaxf(v, 0.f);
}

// ---------------- pooling ----------------

__global__ void k_pool(const __bf16* __restrict__ Hh, const __bf16* __restrict__ Hl,
                       float* __restrict__ pool){
    int g = blockIdx.x, c = threadIdx.x;   // 128 threads
    const __bf16* bh = Hh + (size_t)g*64*H_DIM;
    const __bf16* bl = Hl + (size_t)g*64*H_DIM;
    float s = 0.f, m = -3.4e38f;
    for(int i=0;i<64;i++){
        float v = (float)bh[i*H_DIM + c] + (float)bl[i*H_DIM + c];
        s += v; m = fmaxf(m, v);
    }
    pool[g*256 + c]       = s * (1.f/64.f);
    pool[g*256 + 128 + c] = m;
}

// ---------------- small dense layers (scalar-load A, no LDS) ----------------

__global__ void k_dense(const float* __restrict__ A, int ldA, const float* __restrict__ W,
                        const float* __restrict__ bias, const float* __restrict__ gamma,
                        const float* __restrict__ beta, float* __restrict__ out, int ldOut,
                        int K, int NC, int relu){
    int rowBase = blockIdx.x*16;
    int c = threadIdx.x;     // NC threads
    float acc[16];
    float bb = bias[c];
    #pragma unroll
    for(int r=0;r<16;r++) acc[r] = bb;
    const float* Ab = A + (size_t)rowBase*ldA;
    for(int k=0;k<K;k++){
        float w = W[k*NC + c];
        #pragma unroll
        for(int r=0;r<16;r++) acc[r] = fmaf(Ab[r*ldA + k], w, acc[r]);
    }
    float gsc = 1.f, bsh = 0.f;
    if(gamma){ gsc = gamma[c]*BN_SCALE; bsh = beta[c]; }
    #pragma unroll
    for(int r=0;r<16;r++){
        float v = acc[r];
        if(gamma) v = fmaf(v, gsc, bsh);
        if(relu)  v = fmaxf(v, 0.f);
        out[(rowBase+r)*ldOut + c] = v;
    }
}

__global__ void k_final(const float* __restrict__ z2, const float* __restrict__ Wh3,
                        const float* __restrict__ bh3, float* __restrict__ out){
    int r = blockIdx.x*256 + threadIdx.x;
    if(r < B_GR){
        float acc = bh3[0];
        #pragma unroll
        for(int k=0;k<64;k++) acc = fmaf(z2[r*64+k], Wh3[k], acc);
        out[r] = acc;
    }
}

// ---------------- launch ----------------

extern "C" void kernel_launch(void* const* d_in, const int* in_sizes, int n_in,
                              void* d_out, int out_size, void* d_ws, size_t ws_size,
                              hipStream_t stream){
    (void)in_sizes; (void)n_in; (void)out_size; (void)ws_size;
    const float* x    = (const float*)d_in[0];
    const float* gf   = (const float*)d_in[1];
    const int*   ei   = (const int*)  d_in[2];
    const float* W_emb= (const float*)d_in[4];
    const float* b_emb= (const float*)d_in[5];
    const float* Wg   = (const float*)d_in[6];
    const float* bg   = (const float*)d_in[7];
    const float* bn_g = (const float*)d_in[8];
    const float* bn_b = (const float*)d_in[9];
    const float* Wd1  = (const float*)d_in[10];
    const float* bd1  = (const float*)d_in[11];
    const float* Wd2  = (const float*)d_in[12];
    const float* bd2  = (const float*)d_in[13];
    const float* Wge1 = (const float*)d_in[14];
    const float* bge1 = (const float*)d_in[15];
    const float* g_g  = (const float*)d_in[16];
    const float* g_b  = (const float*)d_in[17];
    const float* Wge2 = (const float*)d_in[18];
    const float* bge2 = (const float*)d_in[19];
    const float* Wh1  = (const float*)d_in[20];
    const float* bh1  = (const float*)d_in[21];
    const float* h_g  = (const float*)d_in[22];
    const float* h_b  = (const float*)d_in[23];
    const float* Wh2  = (const float*)d_in[24];
    const float* bh2  = (const float*)d_in[25];
    const float* Wh3  = (const float*)d_in[26];
    const float* bh3  = (const float*)d_in[27];
    float* outp = (float*)d_out;

    char* base = (char*)d_ws;
    __bf16* Hh = (__bf16*)base;                              // 32 MiB
    __bf16* Hl = (__bf16*)(base + (32u<<20));                // 32 MiB
    char*   R  = base + (64u<<20);                           // 64 MiB multi-use
    // gene phase (in R):
    __bf16* gfh    = (__bf16*)R;                             // 2048*4416*2 = 18,087,936
    __bf16* gfl    = (__bf16*)(R + 18087936);
    float*  gpart  = (float*) (R + 36175872);                // 8*2048*256*4 = 16,777,216
    __bf16* wge_th = (__bf16*)(R + 52953088);                // 256*4416*2 = 2,260,992
    __bf16* wge_tl = (__bf16*)(R + 55214080);                // end: 57,475,072 < 64 MiB
    // embedding phase (in R):
    __bf16* xsh = (__bf16*)R;                                // N*32*2 = 8 MiB
    __bf16* xsl = (__bf16*)(R + (8u<<20));
    // GCN layer phase (in R):
    __bf16* Ah = (__bf16*)R;                                 // 32 MiB
    __bf16* Al = (__bf16*)(R + (32u<<20));
    // tail:
    char* T = base + (128u<<20);
    float* pool = (float*)T;                                 // 2 MiB
    float* g1   = pool + B_GR*256;                           // 2 MiB
    float* t1   = g1   + B_GR*256;                           // 1 MiB
    float* comb = t1   + B_GR*128;                           // 2 MiB
    float* z    = comb + B_GR*256;                           // 1 MiB
    float* z2   = z    + B_GR*128;                           // 0.5 MiB
    int* rowptr = (int*)(z2 + B_GR*64);
    int* cursor = rowptr + (N_NODES+1);
    int* csr    = cursor + N_NODES;
    int* bsums  = csr + E_EDGES;
    float* dinv = (float*)(bsums + 128);
    __bf16* wg_th = (__bf16*)(dinv + N_NODES);               // 3*16384
    __bf16* wg_tl = wg_th + 3*16384;
    __bf16* we_th = wg_tl + 3*16384;                         // 128*32
    __bf16* we_tl = we_th + 128*32;

    const int* src = ei;
    const int* dst = ei + E_EDGES;

    // graph prep
    k_zero_int   <<<N_NODES/256, 256, 0, stream>>>(cursor, N_NODES);
    k_count      <<<E_EDGES/256, 256, 0, stream>>>(dst, cursor);
    k_scan1      <<<128, 1024, 0, stream>>>(cursor, bsums);
    k_scan2      <<<1, 128, 0, stream>>>(bsums);
    k_scan3      <<<128, 1024, 0, stream>>>(cursor, bsums, rowptr);
    k_dinv_cursor<<<N_NODES/256, 256, 0, stream>>>(rowptr, dinv, cursor);
    k_fill       <<<E_EDGES/256, 256, 0, stream>>>(src, dst, cursor, csr);

    // gene branch
    k_split_gf    <<<(B_GR*GF_PAD)/256, 256, 0, stream>>>(gf, gfh, gfl);
    k_split_wge1  <<<(256*GF_PAD)/256, 256, 0, stream>>>(Wge1, wge_th, wge_tl);
    k_gemm_gf_mfma<<<256, 256, 0, stream>>>(gfh, gfl, wge_th, wge_tl, gpart);
    k_gene_reduce <<<(B_GR*256)/256, 256, 0, stream>>>(gpart, bge1, g_g, g_b, g1);

    // embedding
    k_split_x    <<<(N_NODES*32)/256, 256, 0, stream>>>(x, xsh, xsl);
    k_split_wemb <<<(128*32)/256, 256, 0, stream>>>(W_emb, we_th, we_tl);
    k_split_wg   <<<(3*16384)/256, 256, 0, stream>>>(Wg, wg_th, wg_tl);
    k_emb_mfma   <<<N_NODES/128, 256, 0, stream>>>(xsh, xsl, we_th, we_tl, b_emb, Hh, Hl);

    // 3 GCN layers: aggregate-then-matmul (linearity), fused epilogue
    for(int i=0;i<3;i++){
        k_agg   <<<N_NODES/4, 256, 0, stream>>>(Hh, Hl, dinv, rowptr, csr,
                                                (uint32*)Ah, (uint32*)Al);
        k_mm_epi<<<N_NODES/128, 256, 0, stream>>>(Ah, Al, wg_th + i*16384, wg_tl + i*16384,
                                                  bg + i*H_DIM, bn_g + i*H_DIM, bn_b + i*H_DIM,
                                                  Hh, Hl, i > 0);
    }

    // pooling + heads
    k_pool<<<B_GR, 128, 0, stream>>>(Hh, Hl, pool);
    k_dense<<<B_GR/16, 128, 0, stream>>>(pool, 256, Wd1, bd1, nullptr, nullptr, t1,   128, 256, 128, 1);
    k_dense<<<B_GR/16, 128, 0, stream>>>(t1,   128, Wd2, bd2, nullptr, nullptr, comb, 256, 128, 128, 0);
    k_dense<<<B_GR/16, 128, 0, stream>>>(g1,   256, Wge2, bge2, nullptr, nullptr, comb+128, 256, 256, 128, 1);
    k_dense<<<B_GR/16, 128, 0, stream>>>(comb, 256, Wh1, bh1, h_g, h_b, z, 128, 256, 128, 1);
    k_dense<<<B_GR/16, 64,  0, stream>>>(z,    128, Wh2, bh2, nullptr, nullptr, z2, 64, 128, 64, 1);
    k_final<<<B_GR/256, 256, 0, stream>>>(z2, Wh3, bh3, outp);
}

// Round 4
// 738.240 us; speedup vs baseline: 1.7381x; 1.7381x over previous
//
#include <hip/hip_runtime.h>

#define N_NODES 131072
#define E_EDGES 524288
#define B_GR    2048
#define H_DIM   128
#define NF_DIM  30
#define GF_DIM  4415
#define GF_PAD  4416            // 138*32
#define BN_SCALE 0.9999950000374997f   // 1/sqrt(1+1e-5)

typedef __bf16 bf16x8 __attribute__((ext_vector_type(8)));
typedef float  f32x4  __attribute__((ext_vector_type(4)));
typedef unsigned int uint32;

__device__ __forceinline__ void split2(float x, __bf16& hi, __bf16& lo){
    hi = (__bf16)x;
    lo = (__bf16)(x - (float)hi);
}
__device__ __forceinline__ uint32 bfbits(float x){
    __bf16 h = (__bf16)x;
    return (uint32)__builtin_bit_cast(unsigned short, h);
}

// ---------------- graph prep ----------------

__global__ void k_zero_int(int* __restrict__ p, int n){
    int i = blockIdx.x*256 + threadIdx.x;
    if(i < n) p[i] = 0;
}

__global__ void k_count(const int* __restrict__ dst, int* __restrict__ counts){
    int e = blockIdx.x*256 + threadIdx.x;
    if(e < E_EDGES) atomicAdd(&counts[dst[e]], 1);
}

__global__ void k_scan1(int* __restrict__ counts, int* __restrict__ bsums){
    __shared__ int s[1024];
    int t = threadIdx.x;
    int gi = blockIdx.x*1024 + t;
    int v = counts[gi];
    s[t] = v; __syncthreads();
    for(int off=1; off<1024; off<<=1){
        int x = (t>=off) ? s[t-off] : 0;
        __syncthreads();
        s[t] += x;
        __syncthreads();
    }
    counts[gi] = s[t] - v;
    if(t == 1023) bsums[blockIdx.x] = s[t];
}

__global__ void k_scan2(int* __restrict__ bsums){
    __shared__ int s[128];
    int t = threadIdx.x;
    int v = bsums[t]; s[t] = v; __syncthreads();
    for(int off=1; off<128; off<<=1){
        int x = (t>=off) ? s[t-off] : 0;
        __syncthreads();
        s[t] += x;
        __syncthreads();
    }
    bsums[t] = s[t] - v;
}

__global__ void k_scan3(const int* __restrict__ counts, const int* __restrict__ bsums,
                        int* __restrict__ rowptr){
    int i = blockIdx.x*1024 + threadIdx.x;
    rowptr[i] = counts[i] + bsums[blockIdx.x];
    if(i == 0) rowptr[N_NODES] = E_EDGES;
}

__global__ void k_dinv_cursor(const int* __restrict__ rowptr, float* __restrict__ dinv,
                              int* __restrict__ cursor){
    int n = blockIdx.x*256 + threadIdx.x;
    if(n < N_NODES){
        int a = rowptr[n], b = rowptr[n+1];
        dinv[n] = rsqrtf((float)(b - a) + 1.0f);
        cursor[n] = a;
    }
}

__global__ void k_fill(const int* __restrict__ src, const int* __restrict__ dst,
                       int* __restrict__ cursor, int* __restrict__ csr){
    int e = blockIdx.x*256 + threadIdx.x;
    if(e < E_EDGES){
        int p = atomicAdd(&cursor[dst[e]], 1);
        csr[p] = src[e];
    }
}

// ---------------- split-conversion kernels ----------------

__global__ void k_split_x(const float* __restrict__ x, __bf16* __restrict__ xh,
                          __bf16* __restrict__ xl){
    int idx = blockIdx.x*256 + threadIdx.x;          // N*32
    int n = idx >> 5, k = idx & 31;
    float v = (k < NF_DIM) ? x[n*NF_DIM + k] : 0.f;
    split2(v, xh[idx], xl[idx]);
}

__global__ void k_split_wemb(const float* __restrict__ W, __bf16* __restrict__ th,
                             __bf16* __restrict__ tl){
    int idx = blockIdx.x*256 + threadIdx.x;          // 128*32  (c-major, k padded)
    int c = idx >> 5, k = idx & 31;
    float v = (k < NF_DIM) ? W[k*H_DIM + c] : 0.f;
    split2(v, th[idx], tl[idx]);
}

__global__ void k_split_wg(const float* __restrict__ Wg, __bf16* __restrict__ th,
                           __bf16* __restrict__ tl){
    int idx = blockIdx.x*256 + threadIdx.x;          // 3*128*128
    int l = idx >> 14, i = idx & 16383;
    int k = i >> 7, c = i & 127;
    float v = Wg[idx];
    int o = (l << 14) + (c << 7) + k;                // transposed: [l][c][k]
    split2(v, th[o], tl[o]);
}

__global__ void k_split_gf(const float* __restrict__ gf, __bf16* __restrict__ ah,
                           __bf16* __restrict__ al){
    unsigned idx = blockIdx.x*256 + threadIdx.x;     // 2048*4416
    unsigned r = idx / GF_PAD, k = idx - r*GF_PAD;
    float v = (k < GF_DIM) ? gf[(size_t)r*GF_DIM + k] : 0.f;
    split2(v, ah[idx], al[idx]);
}

__global__ void k_split_wge1(const float* __restrict__ W, __bf16* __restrict__ th,
                             __bf16* __restrict__ tl){
    unsigned idx = blockIdx.x*256 + threadIdx.x;     // 256*4416 (c-major, k padded)
    unsigned c = idx / GF_PAD, k = idx - c*GF_PAD;
    float v = (k < GF_DIM) ? W[(size_t)k*256 + c] : 0.f;
    split2(v, th[idx], tl[idx]);
}

// ---------------- embedding via MFMA:  relu(x @ W_emb + b) -> (Hh,Hl) ----------------

__global__ __launch_bounds__(256)
void k_emb_mfma(const __bf16* __restrict__ xh, const __bf16* __restrict__ xl,
                const __bf16* __restrict__ wth, const __bf16* __restrict__ wtl,
                const float* __restrict__ bias, __bf16* __restrict__ Hh,
                __bf16* __restrict__ Hl){
    int wave = threadIdx.x >> 6, lane = threadIdx.x & 63;
    int lr = lane & 15, lq = lane >> 4;
    int rbase = blockIdx.x*128 + wave*32;
    const f32x4 zero4 = {0.f,0.f,0.f,0.f};
    bf16x8 A0h = *(const bf16x8*)(xh + (size_t)(rbase + lr)*32 + lq*8);
    bf16x8 A0l = *(const bf16x8*)(xl + (size_t)(rbase + lr)*32 + lq*8);
    bf16x8 A1h = *(const bf16x8*)(xh + (size_t)(rbase + 16 + lr)*32 + lq*8);
    bf16x8 A1l = *(const bf16x8*)(xl + (size_t)(rbase + 16 + lr)*32 + lq*8);
    #pragma unroll
    for(int ct=0;ct<8;ct++){
        int col = ct*16 + lr;
        bf16x8 Bh = *(const bf16x8*)(wth + col*32 + lq*8);
        bf16x8 Bl = *(const bf16x8*)(wtl + col*32 + lq*8);
        f32x4 a0 = zero4, a1 = zero4;
        a0 = __builtin_amdgcn_mfma_f32_16x16x32_bf16(A0h, Bh, a0, 0,0,0);
        a0 = __builtin_amdgcn_mfma_f32_16x16x32_bf16(A0l, Bh, a0, 0,0,0);
        a0 = __builtin_amdgcn_mfma_f32_16x16x32_bf16(A0h, Bl, a0, 0,0,0);
        a1 = __builtin_amdgcn_mfma_f32_16x16x32_bf16(A1h, Bh, a1, 0,0,0);
        a1 = __builtin_amdgcn_mfma_f32_16x16x32_bf16(A1l, Bh, a1, 0,0,0);
        a1 = __builtin_amdgcn_mfma_f32_16x16x32_bf16(A1h, Bl, a1, 0,0,0);
        float bb = bias[col];
        #pragma unroll
        for(int r=0;r<4;r++){
            size_t i0 = (size_t)(rbase + lq*4 + r)*H_DIM + col;
            size_t i1 = (size_t)(rbase + 16 + lq*4 + r)*H_DIM + col;
            float v0 = fmaxf(a0[r] + bb, 0.f);
            float v1 = fmaxf(a1[r] + bb, 0.f);
            split2(v0, Hh[i0], Hl[i0]);
            split2(v1, Hh[i1], Hl[i1]);
        }
    }
}

// ---------------- normalized aggregation on H (before matmul) ----------------

__global__ __launch_bounds__(256)
void k_agg(const __bf16* __restrict__ Hh, const __bf16* __restrict__ Hl,
           const float* __restrict__ dinv, const int* __restrict__ rowptr,
           const int* __restrict__ csr, uint32* __restrict__ Ah2,
           uint32* __restrict__ Al2){
    int wave = threadIdx.x >> 6, lane = threadIdx.x & 63;
    int n = blockIdx.x*4 + wave;
    float dn = dinv[n];
    size_t i0 = (size_t)n*64 + lane;        // uint32 units (2 bf16 per uint)
    const uint32* Hh2 = (const uint32*)Hh;
    const uint32* Hl2 = (const uint32*)Hl;
    uint32 sh = Hh2[i0], sl = Hl2[i0];
    float sx = __uint_as_float(sh<<16) + __uint_as_float(sl<<16);
    float sy = __uint_as_float(sh & 0xffff0000u) + __uint_as_float(sl & 0xffff0000u);
    float ax = sx*dn, ay = sy*dn;
    int j0 = rowptr[n], j1 = rowptr[n+1];
    int jm = j1 - 1;
    for(int j=j0; j<j1; j+=4){
        int i1 = (j+1<=jm)? j+1 : jm;
        int i2 = (j+2<=jm)? j+2 : jm;
        int i3 = (j+3<=jm)? j+3 : jm;
        int s0 = csr[j], s1 = csr[i1], s2 = csr[i2], s3 = csr[i3];
        float w0 = dinv[s0];
        float w1 = (j+1<=jm)? dinv[s1] : 0.f;
        float w2 = (j+2<=jm)? dinv[s2] : 0.f;
        float w3 = (j+3<=jm)? dinv[s3] : 0.f;
        uint32 r0 = Hh2[(size_t)s0*64 + lane];
        uint32 r1 = Hh2[(size_t)s1*64 + lane];
        uint32 r2 = Hh2[(size_t)s2*64 + lane];
        uint32 r3 = Hh2[(size_t)s3*64 + lane];
        ax = fmaf(__uint_as_float(r0<<16), w0, ax);
        ay = fmaf(__uint_as_float(r0 & 0xffff0000u), w0, ay);
        ax = fmaf(__uint_as_float(r1<<16), w1, ax);
        ay = fmaf(__uint_as_float(r1 & 0xffff0000u), w1, ay);
        ax = fmaf(__uint_as_float(r2<<16), w2, ax);
        ay = fmaf(__uint_as_float(r2 & 0xffff0000u), w2, ay);
        ax = fmaf(__uint_as_float(r3<<16), w3, ax);
        ay = fmaf(__uint_as_float(r3 & 0xffff0000u), w3, ay);
    }
    ax *= dn; ay *= dn;
    uint32 hx = bfbits(ax), hy = bfbits(ay);
    Ah2[i0] = hx | (hy<<16);
    float lx = ax - __uint_as_float(hx<<16);
    float ly = ay - __uint_as_float(hy<<16);
    Al2[i0] = bfbits(lx) | (bfbits(ly)<<16);
}

// ---------------- matmul + bias + BN + ReLU + residual -> (Hh,Hl) ----------------

__global__ __launch_bounds__(256)
void k_mm_epi(const __bf16* __restrict__ Ah, const __bf16* __restrict__ Al,
              const __bf16* __restrict__ Bth, const __bf16* __restrict__ Btl,
              const float* __restrict__ bias, const float* __restrict__ gamma,
              const float* __restrict__ beta, __bf16* __restrict__ Hh,
              __bf16* __restrict__ Hl, int residual){
    int wave = threadIdx.x >> 6, lane = threadIdx.x & 63;
    int lr = lane & 15, lq = lane >> 4;
    int rbase = blockIdx.x*128 + wave*32;
    const f32x4 zero4 = {0.f,0.f,0.f,0.f};
    size_t o0 = (size_t)(rbase + lr)*H_DIM + lq*8;
    size_t o1 = o0 + (size_t)16*H_DIM;
    bf16x8 A0h[4], A0l[4], A1h[4], A1l[4];
    #pragma unroll
    for(int ks=0;ks<4;ks++){
        A0h[ks] = *(const bf16x8*)(Ah + o0 + ks*32);
        A0l[ks] = *(const bf16x8*)(Al + o0 + ks*32);
        A1h[ks] = *(const bf16x8*)(Ah + o1 + ks*32);
        A1l[ks] = *(const bf16x8*)(Al + o1 + ks*32);
    }
    #pragma unroll
    for(int ct=0;ct<8;ct++){
        int col = ct*16 + lr;
        f32x4 a0 = zero4, a1 = zero4;
        #pragma unroll
        for(int ks=0;ks<4;ks++){
            bf16x8 Bh = *(const bf16x8*)(Bth + col*H_DIM + ks*32 + lq*8);
            bf16x8 Bl = *(const bf16x8*)(Btl + col*H_DIM + ks*32 + lq*8);
            a0 = __builtin_amdgcn_mfma_f32_16x16x32_bf16(A0h[ks], Bh, a0, 0,0,0);
            a0 = __builtin_amdgcn_mfma_f32_16x16x32_bf16(A0l[ks], Bh, a0, 0,0,0);
            a0 = __builtin_amdgcn_mfma_f32_16x16x32_bf16(A0h[ks], Bl, a0, 0,0,0);
            a1 = __builtin_amdgcn_mfma_f32_16x16x32_bf16(A1h[ks], Bh, a1, 0,0,0);
            a1 = __builtin_amdgcn_mfma_f32_16x16x32_bf16(A1l[ks], Bh, a1, 0,0,0);
            a1 = __builtin_amdgcn_mfma_f32_16x16x32_bf16(A1h[ks], Bl, a1, 0,0,0);
        }
        float bb = bias[col];
        float gs = gamma[col]*BN_SCALE;
        float bt = beta[col];
        #pragma unroll
        for(int r=0;r<4;r++){
            size_t i0 = (size_t)(rbase + lq*4 + r)*H_DIM + col;
            size_t i1 = (size_t)(rbase + 16 + lq*4 + r)*H_DIM + col;
            float v0 = fmaxf(fmaf(a0[r] + bb, gs, bt), 0.f);
            float v1 = fmaxf(fmaf(a1[r] + bb, gs, bt), 0.f);
            if(residual){
                v0 += (float)Hh[i0] + (float)Hl[i0];
                v1 += (float)Hh[i1] + (float)Hl[i1];
            }
            split2(v0, Hh[i0], Hl[i0]);
            split2(v1, Hh[i1], Hl[i1]);
        }
    }
}

// ---------------- gene GEMM via MFMA, split-K partials (no atomics) ----------------

__global__ __launch_bounds__(256)
void k_gemm_gf_mfma(const __bf16* __restrict__ Ah, const __bf16* __restrict__ Al,
                    const __bf16* __restrict__ Bth, const __bf16* __restrict__ Btl,
                    float* __restrict__ gpart){
    int rt = blockIdx.x & 31;       // 32 row tiles of 64
    int sp = blockIdx.x >> 5;       // 8 k-splits
    int ks0 = (sp*138) >> 3, ks1 = ((sp+1)*138) >> 3;
    int wave = threadIdx.x >> 6, lane = threadIdx.x & 63;
    int lr = lane & 15, lq = lane >> 4;
    int rbase = rt*64 + (wave & 1)*32;
    int cbase = (wave >> 1)*128;
    const f32x4 zero4 = {0.f,0.f,0.f,0.f};
    f32x4 acc[8][2];
    #pragma unroll
    for(int ct=0;ct<8;ct++){ acc[ct][0] = zero4; acc[ct][1] = zero4; }
    for(int ks=ks0; ks<ks1; ks++){
        int kc = ks*32;
        size_t oa0 = (size_t)(rbase + lr)*GF_PAD + kc + lq*8;
        size_t oa1 = oa0 + (size_t)16*GF_PAD;
        bf16x8 A0h = *(const bf16x8*)(Ah + oa0);
        bf16x8 A0l = *(const bf16x8*)(Al + oa0);
        bf16x8 A1h = *(const bf16x8*)(Ah + oa1);
        bf16x8 A1l = *(const bf16x8*)(Al + oa1);
        #pragma unroll
        for(int ct=0;ct<8;ct++){
            size_t bo = (size_t)(cbase + ct*16 + lr)*GF_PAD + kc + lq*8;
            bf16x8 Bh = *(const bf16x8*)(Bth + bo);
            bf16x8 Bl = *(const bf16x8*)(Btl + bo);
            acc[ct][0] = __builtin_amdgcn_mfma_f32_16x16x32_bf16(A0h, Bh, acc[ct][0], 0,0,0);
            acc[ct][0] = __builtin_amdgcn_mfma_f32_16x16x32_bf16(A0l, Bh, acc[ct][0], 0,0,0);
            acc[ct][0] = __builtin_amdgcn_mfma_f32_16x16x32_bf16(A0h, Bl, acc[ct][0], 0,0,0);
            acc[ct][1] = __builtin_amdgcn_mfma_f32_16x16x32_bf16(A1h, Bh, acc[ct][1], 0,0,0);
            acc[ct][1] = __builtin_amdgcn_mfma_f32_16x16x32_bf16(A1l, Bh, acc[ct][1], 0,0,0);
            acc[ct][1] = __builtin_amdgcn_mfma_f32_16x16x32_bf16(A1h, Bl, acc[ct][1], 0,0,0);
        }
    }
    float* po = gpart + (size_t)sp*(B_GR*256);
    #pragma unroll
    for(int ct=0;ct<8;ct++)
        #pragma unroll
        for(int s=0;s<2;s++)
            #pragma unroll
            for(int r=0;r<4;r++)
                po[(size_t)(rbase + s*16 + lq*4 + r)*256 + cbase + ct*16 + lr] = acc[ct][s][r];
}

__global__ void k_gene_reduce(const float* __restrict__ gpart, const float* __restrict__ bias,
                              const float* __restrict__ gamma, const float* __restrict__ beta,
                              float* __restrict__ g1){
    int i = blockIdx.x*256 + threadIdx.x;   // B*256
    int c = i & 255;
    float v = bias[c];
    #pragma unroll
    for(int sp=0;sp<8;sp++) v += gpart[(size_t)sp*(B_GR*256) + i];
    v = fmaf(v, gamma[c]*BN_SCALE, beta[c]);
    g1[i] = fmaxf(v, 0.f);
}

// ---------------- pooling ----------------

__global__ void k_pool(const __bf16* __restrict__ Hh, const __bf16* __restrict__ Hl,
                       float* __restrict__ pool){
    int g = blockIdx.x, c = threadIdx.x;   // 128 threads
    const __bf16* bh = Hh + (size_t)g*64*H_DIM;
    const __bf16* bl = Hl + (size_t)g*64*H_DIM;
    float s = 0.f, m = -3.4e38f;
    for(int i=0;i<64;i++){
        float v = (float)bh[i*H_DIM + c] + (float)bl[i*H_DIM + c];
        s += v; m = fmaxf(m, v);
    }
    pool[g*256 + c]       = s * (1.f/64.f);
    pool[g*256 + 128 + c] = m;
}

// ---------------- small dense layers: LDS-staged A, 4 rows/block ----------------
// blockDim.x == NC; grid = B/4.  Per k-step: 1 coalesced W load (L2-hit),
// 4 same-address LDS broadcasts (free), 4 FMA.  512 blocks -> latency hidden.

__global__ void k_dense(const float* __restrict__ A, int ldA, const float* __restrict__ W,
                        const float* __restrict__ bias, const float* __restrict__ gamma,
                        const float* __restrict__ beta, float* __restrict__ out, int ldOut,
                        int K, int logK, int NC, int relu){
    extern __shared__ float sA[];   // 4*K floats
    int rowBase = blockIdx.x*4;
    int c = threadIdx.x;
    for(int idx=threadIdx.x; idx<4*K; idx+=NC){
        int r = idx >> logK, k = idx & (K-1);
        sA[idx] = A[(rowBase+r)*ldA + k];
    }
    __syncthreads();
    float bb = bias[c];
    float acc0=bb, acc1=bb, acc2=bb, acc3=bb;
    for(int k=0;k<K;k++){
        float w = W[k*NC + c];
        acc0 = fmaf(sA[k],        w, acc0);
        acc1 = fmaf(sA[K+k],      w, acc1);
        acc2 = fmaf(sA[2*K+k],    w, acc2);
        acc3 = fmaf(sA[3*K+k],    w, acc3);
    }
    float gsc = 1.f, bsh = 0.f;
    if(gamma){ gsc = gamma[c]*BN_SCALE; bsh = beta[c]; }
    float v0=acc0, v1=acc1, v2=acc2, v3=acc3;
    if(gamma){ v0=fmaf(v0,gsc,bsh); v1=fmaf(v1,gsc,bsh); v2=fmaf(v2,gsc,bsh); v3=fmaf(v3,gsc,bsh); }
    if(relu){ v0=fmaxf(v0,0.f); v1=fmaxf(v1,0.f); v2=fmaxf(v2,0.f); v3=fmaxf(v3,0.f); }
    out[(rowBase+0)*ldOut + c] = v0;
    out[(rowBase+1)*ldOut + c] = v1;
    out[(rowBase+2)*ldOut + c] = v2;
    out[(rowBase+3)*ldOut + c] = v3;
}

// ---------------- final [2048,64] @ [64,1]: shuffle-reduced ----------------

__global__ void k_final(const float* __restrict__ z2, const float* __restrict__ Wh3,
                        const float* __restrict__ bh3, float* __restrict__ out){
    int lane = threadIdx.x & 63, wr = threadIdx.x >> 6;
    int r = blockIdx.x*4 + wr;
    float v = z2[r*64 + lane] * Wh3[lane];
    #pragma unroll
    for(int off=32; off; off>>=1) v += __shfl_down(v, off);
    if(lane == 0) out[r] = v + bh3[0];
}

// ---------------- launch ----------------

extern "C" void kernel_launch(void* const* d_in, const int* in_sizes, int n_in,
                              void* d_out, int out_size, void* d_ws, size_t ws_size,
                              hipStream_t stream){
    (void)in_sizes; (void)n_in; (void)out_size; (void)ws_size;
    const float* x    = (const float*)d_in[0];
    const float* gf   = (const float*)d_in[1];
    const int*   ei   = (const int*)  d_in[2];
    const float* W_emb= (const float*)d_in[4];
    const float* b_emb= (const float*)d_in[5];
    const float* Wg   = (const float*)d_in[6];
    const float* bg   = (const float*)d_in[7];
    const float* bn_g = (const float*)d_in[8];
    const float* bn_b = (const float*)d_in[9];
    const float* Wd1  = (const float*)d_in[10];
    const float* bd1  = (const float*)d_in[11];
    const float* Wd2  = (const float*)d_in[12];
    const float* bd2  = (const float*)d_in[13];
    const float* Wge1 = (const float*)d_in[14];
    const float* bge1 = (const float*)d_in[15];
    const float* g_g  = (const float*)d_in[16];
    const float* g_b  = (const float*)d_in[17];
    const float* Wge2 = (const float*)d_in[18];
    const float* bge2 = (const float*)d_in[19];
    const float* Wh1  = (const float*)d_in[20];
    const float* bh1  = (const float*)d_in[21];
    const float* h_g  = (const float*)d_in[22];
    const float* h_b  = (const float*)d_in[23];
    const float* Wh2  = (const float*)d_in[24];
    const float* bh2  = (const float*)d_in[25];
    const float* Wh3  = (const float*)d_in[26];
    const float* bh3  = (const float*)d_in[27];
    float* outp = (float*)d_out;

    char* base = (char*)d_ws;
    __bf16* Hh = (__bf16*)base;                              // 32 MiB
    __bf16* Hl = (__bf16*)(base + (32u<<20));                // 32 MiB
    char*   R  = base + (64u<<20);                           // 64 MiB multi-use
    // gene phase (in R):
    __bf16* gfh    = (__bf16*)R;                             // 18,087,936 B
    __bf16* gfl    = (__bf16*)(R + 18087936);
    float*  gpart  = (float*) (R + 36175872);                // 16,777,216 B
    __bf16* wge_th = (__bf16*)(R + 52953088);                // 2,260,992 B
    __bf16* wge_tl = (__bf16*)(R + 55214080);                // end < 64 MiB
    // embedding phase (in R):
    __bf16* xsh = (__bf16*)R;                                // 8 MiB
    __bf16* xsl = (__bf16*)(R + (8u<<20));
    // GCN layer phase (in R):
    __bf16* Ah = (__bf16*)R;                                 // 32 MiB
    __bf16* Al = (__bf16*)(R + (32u<<20));
    // tail:
    char* T = base + (128u<<20);
    float* pool = (float*)T;
    float* g1   = pool + B_GR*256;
    float* t1   = g1   + B_GR*256;
    float* comb = t1   + B_GR*128;
    float* z    = comb + B_GR*256;
    float* z2   = z    + B_GR*128;
    int* rowptr = (int*)(z2 + B_GR*64);
    int* cursor = rowptr + (N_NODES+1);
    int* csr    = cursor + N_NODES;
    int* bsums  = csr + E_EDGES;
    float* dinv = (float*)(bsums + 128);
    __bf16* wg_th = (__bf16*)(dinv + N_NODES);               // 3*16384
    __bf16* wg_tl = wg_th + 3*16384;
    __bf16* we_th = wg_tl + 3*16384;                         // 128*32
    __bf16* we_tl = we_th + 128*32;

    const int* src = ei;
    const int* dst = ei + E_EDGES;

    // graph prep
    k_zero_int   <<<N_NODES/256, 256, 0, stream>>>(cursor, N_NODES);
    k_count      <<<E_EDGES/256, 256, 0, stream>>>(dst, cursor);
    k_scan1      <<<128, 1024, 0, stream>>>(cursor, bsums);
    k_scan2      <<<1, 128, 0, stream>>>(bsums);
    k_scan3      <<<128, 1024, 0, stream>>>(cursor, bsums, rowptr);
    k_dinv_cursor<<<N_NODES/256, 256, 0, stream>>>(rowptr, dinv, cursor);
    k_fill       <<<E_EDGES/256, 256, 0, stream>>>(src, dst, cursor, csr);

    // gene branch
    k_split_gf    <<<(B_GR*GF_PAD)/256, 256, 0, stream>>>(gf, gfh, gfl);
    k_split_wge1  <<<(256*GF_PAD)/256, 256, 0, stream>>>(Wge1, wge_th, wge_tl);
    k_gemm_gf_mfma<<<256, 256, 0, stream>>>(gfh, gfl, wge_th, wge_tl, gpart);
    k_gene_reduce <<<(B_GR*256)/256, 256, 0, stream>>>(gpart, bge1, g_g, g_b, g1);

    // embedding
    k_split_x    <<<(N_NODES*32)/256, 256, 0, stream>>>(x, xsh, xsl);
    k_split_wemb <<<(128*32)/256, 256, 0, stream>>>(W_emb, we_th, we_tl);
    k_split_wg   <<<(3*16384)/256, 256, 0, stream>>>(Wg, wg_th, wg_tl);
    k_emb_mfma   <<<N_NODES/128, 256, 0, stream>>>(xsh, xsl, we_th, we_tl, b_emb, Hh, Hl);

    // 3 GCN layers: aggregate-then-matmul (linearity), fused epilogue
    for(int i=0;i<3;i++){
        k_agg   <<<N_NODES/4, 256, 0, stream>>>(Hh, Hl, dinv, rowptr, csr,
                                                (uint32*)Ah, (uint32*)Al);
        k_mm_epi<<<N_NODES/128, 256, 0, stream>>>(Ah, Al, wg_th + i*16384, wg_tl + i*16384,
                                                  bg + i*H_DIM, bn_g + i*H_DIM, bn_b + i*H_DIM,
                                                  Hh, Hl, i > 0);
    }

    // pooling + heads
    k_pool<<<B_GR, 128, 0, stream>>>(Hh, Hl, pool);
    k_dense<<<B_GR/4, 128, 4*256*4, stream>>>(pool, 256, Wd1, bd1, nullptr, nullptr, t1,   128, 256, 8, 128, 1);
    k_dense<<<B_GR/4, 128, 4*128*4, stream>>>(t1,   128, Wd2, bd2, nullptr, nullptr, comb, 256, 128, 7, 128, 0);
    k_dense<<<B_GR/4, 128, 4*256*4, stream>>>(g1,   256, Wge2, bge2, nullptr, nullptr, comb+128, 256, 256, 8, 128, 1);
    k_dense<<<B_GR/4, 128, 4*256*4, stream>>>(comb, 256, Wh1, bh1, h_g, h_b, z, 128, 256, 8, 128, 1);
    k_dense<<<B_GR/4, 64,  4*128*4, stream>>>(z,    128, Wh2, bh2, nullptr, nullptr, z2, 64, 128, 7, 64, 1);
    k_final<<<B_GR/4, 256, 0, stream>>>(z2, Wh3, bh3, outp);
}

// Round 5
// 725.703 us; speedup vs baseline: 1.7682x; 1.0173x over previous
//
#include <hip/hip_runtime.h>

#define N_NODES 131072
#define E_EDGES 524288
#define B_GR    2048
#define H_DIM   128
#define NF_DIM  30
#define GF_DIM  4415
#define GF_PAD  4416            // 138*32
#define BN_SCALE 0.9999950000374997f   // 1/sqrt(1+1e-5)

typedef __bf16 bf16x8 __attribute__((ext_vector_type(8)));
typedef float  f32x4  __attribute__((ext_vector_type(4)));
typedef unsigned int uint32;

__device__ __forceinline__ void split2(float x, __bf16& hi, __bf16& lo){
    hi = (__bf16)x;
    lo = (__bf16)(x - (float)hi);
}
__device__ __forceinline__ uint32 bfbits(float x){
    __bf16 h = (__bf16)x;
    return (uint32)__builtin_bit_cast(unsigned short, h);
}
// packed uint32: low 16 bits = even col, high 16 bits = odd col
__device__ __forceinline__ float unpack_even(uint32 u){ return __uint_as_float(u<<16); }
__device__ __forceinline__ float unpack_odd (uint32 u){ return __uint_as_float(u & 0xffff0000u); }
__device__ __forceinline__ uint32 pack2(float e, float o){ return bfbits(e) | (bfbits(o)<<16); }

// ---------------- graph prep ----------------

__global__ void k_zero_int(int* __restrict__ p, int n){
    int i = blockIdx.x*256 + threadIdx.x;
    if(i < n) p[i] = 0;
}

__global__ void k_count(const int* __restrict__ dst, int* __restrict__ counts){
    int e = blockIdx.x*256 + threadIdx.x;
    if(e < E_EDGES) atomicAdd(&counts[dst[e]], 1);
}

__global__ void k_scan1(int* __restrict__ counts, int* __restrict__ bsums){
    __shared__ int s[1024];
    int t = threadIdx.x;
    int gi = blockIdx.x*1024 + t;
    int v = counts[gi];
    s[t] = v; __syncthreads();
    for(int off=1; off<1024; off<<=1){
        int x = (t>=off) ? s[t-off] : 0;
        __syncthreads();
        s[t] += x;
        __syncthreads();
    }
    counts[gi] = s[t] - v;
    if(t == 1023) bsums[blockIdx.x] = s[t];
}

__global__ void k_scan2(int* __restrict__ bsums){
    __shared__ int s[128];
    int t = threadIdx.x;
    int v = bsums[t]; s[t] = v; __syncthreads();
    for(int off=1; off<128; off<<=1){
        int x = (t>=off) ? s[t-off] : 0;
        __syncthreads();
        s[t] += x;
        __syncthreads();
    }
    bsums[t] = s[t] - v;
}

__global__ void k_scan3(const int* __restrict__ counts, const int* __restrict__ bsums,
                        int* __restrict__ rowptr){
    int i = blockIdx.x*1024 + threadIdx.x;
    rowptr[i] = counts[i] + bsums[blockIdx.x];
    if(i == 0) rowptr[N_NODES] = E_EDGES;
}

__global__ void k_dinv_cursor(const int* __restrict__ rowptr, float* __restrict__ dinv,
                              int* __restrict__ cursor){
    int n = blockIdx.x*256 + threadIdx.x;
    if(n < N_NODES){
        int a = rowptr[n], b = rowptr[n+1];
        dinv[n] = rsqrtf((float)(b - a) + 1.0f);
        cursor[n] = a;
    }
}

__global__ void k_fill(const int* __restrict__ src, const int* __restrict__ dst,
                       int* __restrict__ cursor, int* __restrict__ csr){
    int e = blockIdx.x*256 + threadIdx.x;
    if(e < E_EDGES){
        int p = atomicAdd(&cursor[dst[e]], 1);
        csr[p] = src[e];
    }
}

// ---------------- split-conversion kernels ----------------

__global__ void k_split_x(const float* __restrict__ x, __bf16* __restrict__ xh,
                          __bf16* __restrict__ xl){
    int idx = blockIdx.x*256 + threadIdx.x;          // N*32
    int n = idx >> 5, k = idx & 31;
    float v = (k < NF_DIM) ? x[n*NF_DIM + k] : 0.f;
    split2(v, xh[idx], xl[idx]);
}

__global__ void k_split_wemb(const float* __restrict__ W, __bf16* __restrict__ th,
                             __bf16* __restrict__ tl){
    int idx = blockIdx.x*256 + threadIdx.x;          // 128*32  (c-major, k padded)
    int c = idx >> 5, k = idx & 31;
    float v = (k < NF_DIM) ? W[k*H_DIM + c] : 0.f;
    split2(v, th[idx], tl[idx]);
}

__global__ void k_split_wg(const float* __restrict__ Wg, __bf16* __restrict__ th,
                           __bf16* __restrict__ tl){
    int idx = blockIdx.x*256 + threadIdx.x;          // 3*128*128
    int l = idx >> 14, i = idx & 16383;
    int k = i >> 7, c = i & 127;
    float v = Wg[idx];
    int o = (l << 14) + (c << 7) + k;                // transposed: [l][c][k]
    split2(v, th[o], tl[o]);
}

__global__ void k_split_gf(const float* __restrict__ gf, __bf16* __restrict__ ah,
                           __bf16* __restrict__ al){
    unsigned idx = blockIdx.x*256 + threadIdx.x;     // 2048*4416
    unsigned r = idx / GF_PAD, k = idx - r*GF_PAD;
    float v = (k < GF_DIM) ? gf[(size_t)r*GF_DIM + k] : 0.f;
    split2(v, ah[idx], al[idx]);
}

__global__ void k_split_wge1(const float* __restrict__ W, __bf16* __restrict__ th,
                             __bf16* __restrict__ tl){
    unsigned idx = blockIdx.x*256 + threadIdx.x;     // 256*4416 (c-major, k padded)
    unsigned c = idx / GF_PAD, k = idx - c*GF_PAD;
    float v = (k < GF_DIM) ? W[(size_t)k*256 + c] : 0.f;
    split2(v, th[idx], tl[idx]);
}

// ---------------- embedding via MFMA:  relu(x @ W_emb + b) -> packed (Hh,Hl) ----------------

__global__ __launch_bounds__(256)
void k_emb_mfma(const __bf16* __restrict__ xh, const __bf16* __restrict__ xl,
                const __bf16* __restrict__ wth, const __bf16* __restrict__ wtl,
                const float* __restrict__ bias, uint32* __restrict__ Hh2,
                uint32* __restrict__ Hl2){
    __shared__ float sT[4][32*36];
    int wave = threadIdx.x >> 6, lane = threadIdx.x & 63;
    int lr = lane & 15, lq = lane >> 4;
    int rbase = blockIdx.x*128 + wave*32;
    const f32x4 zero4 = {0.f,0.f,0.f,0.f};
    bf16x8 A0h = *(const bf16x8*)(xh + (size_t)(rbase + lr)*32 + lq*8);
    bf16x8 A0l = *(const bf16x8*)(xl + (size_t)(rbase + lr)*32 + lq*8);
    bf16x8 A1h = *(const bf16x8*)(xh + (size_t)(rbase + 16 + lr)*32 + lq*8);
    bf16x8 A1l = *(const bf16x8*)(xl + (size_t)(rbase + 16 + lr)*32 + lq*8);
    int orow = lane >> 2;          // 0..15
    int oq   = lane & 3;           // 0..3
    float* sW = sT[wave];
    for(int cp=0; cp<4; cp++){
        #pragma unroll
        for(int cc=0; cc<2; cc++){
            int ct = cp*2 + cc;
            int col = ct*16 + lr;
            bf16x8 Bh = *(const bf16x8*)(wth + col*32 + lq*8);
            bf16x8 Bl = *(const bf16x8*)(wtl + col*32 + lq*8);
            f32x4 a0 = zero4, a1 = zero4;
            a0 = __builtin_amdgcn_mfma_f32_16x16x32_bf16(A0h, Bh, a0, 0,0,0);
            a0 = __builtin_amdgcn_mfma_f32_16x16x32_bf16(A0l, Bh, a0, 0,0,0);
            a0 = __builtin_amdgcn_mfma_f32_16x16x32_bf16(A0h, Bl, a0, 0,0,0);
            a1 = __builtin_amdgcn_mfma_f32_16x16x32_bf16(A1h, Bh, a1, 0,0,0);
            a1 = __builtin_amdgcn_mfma_f32_16x16x32_bf16(A1l, Bh, a1, 0,0,0);
            a1 = __builtin_amdgcn_mfma_f32_16x16x32_bf16(A1h, Bl, a1, 0,0,0);
            #pragma unroll
            for(int r=0;r<4;r++){
                sW[(lq*4+r)*36 + cc*16 + lr]    = a0[r];
                sW[(16+lq*4+r)*36 + cc*16 + lr] = a1[r];
            }
        }
        __syncthreads();
        int c0 = cp*32 + oq*8;
        float4 b0 = *(const float4*)(bias + c0);
        float4 b1 = *(const float4*)(bias + c0 + 4);
        float bb[8] = {b0.x,b0.y,b0.z,b0.w,b1.x,b1.y,b1.z,b1.w};
        #pragma unroll
        for(int g=0; g<2; g++){
            int row = g*16 + orow;
            float v[8];
            *(float4*)&v[0] = *(float4*)&sW[row*36 + oq*8];
            *(float4*)&v[4] = *(float4*)&sW[row*36 + oq*8 + 4];
            uint32 oh[4], ol[4];
            #pragma unroll
            for(int p=0;p<4;p++){
                float ve = fmaxf(v[2*p]   + bb[2*p],   0.f);
                float vo = fmaxf(v[2*p+1] + bb[2*p+1], 0.f);
                uint32 he = bfbits(ve), ho = bfbits(vo);
                oh[p] = he | (ho<<16);
                float le = ve - __uint_as_float(he<<16);
                float lo = vo - __uint_as_float(ho<<16);
                ol[p] = pack2(le, lo);
            }
            size_t oidx = (size_t)(rbase + row)*64 + (c0>>1);
            *(uint4*)(Hh2 + oidx) = make_uint4(oh[0],oh[1],oh[2],oh[3]);
            *(uint4*)(Hl2 + oidx) = make_uint4(ol[0],ol[1],ol[2],ol[3]);
        }
        __syncthreads();
    }
}

// ---------------- normalized aggregation on H (before matmul) ----------------

__global__ __launch_bounds__(256)
void k_agg(const __bf16* __restrict__ Hh, const __bf16* __restrict__ Hl,
           const float* __restrict__ dinv, const int* __restrict__ rowptr,
           const int* __restrict__ csr, uint32* __restrict__ Ah2,
           uint32* __restrict__ Al2){
    int wave = threadIdx.x >> 6, lane = threadIdx.x & 63;
    int n = blockIdx.x*4 + wave;
    float dn = dinv[n];
    size_t i0 = (size_t)n*64 + lane;        // uint32 units (2 bf16 per uint)
    const uint32* Hh2 = (const uint32*)Hh;
    const uint32* Hl2 = (const uint32*)Hl;
    uint32 sh = Hh2[i0], sl = Hl2[i0];
    float sx = unpack_even(sh) + unpack_even(sl);
    float sy = unpack_odd(sh)  + unpack_odd(sl);
    float ax = sx*dn, ay = sy*dn;
    int j0 = rowptr[n], j1 = rowptr[n+1];
    int jm = j1 - 1;
    for(int j=j0; j<j1; j+=4){
        int i1 = (j+1<=jm)? j+1 : jm;
        int i2 = (j+2<=jm)? j+2 : jm;
        int i3 = (j+3<=jm)? j+3 : jm;
        int s0 = csr[j], s1 = csr[i1], s2 = csr[i2], s3 = csr[i3];
        float w0 = dinv[s0];
        float w1 = (j+1<=jm)? dinv[s1] : 0.f;
        float w2 = (j+2<=jm)? dinv[s2] : 0.f;
        float w3 = (j+3<=jm)? dinv[s3] : 0.f;
        uint32 r0 = Hh2[(size_t)s0*64 + lane];
        uint32 r1 = Hh2[(size_t)s1*64 + lane];
        uint32 r2 = Hh2[(size_t)s2*64 + lane];
        uint32 r3 = Hh2[(size_t)s3*64 + lane];
        ax = fmaf(unpack_even(r0), w0, ax);
        ay = fmaf(unpack_odd(r0),  w0, ay);
        ax = fmaf(unpack_even(r1), w1, ax);
        ay = fmaf(unpack_odd(r1),  w1, ay);
        ax = fmaf(unpack_even(r2), w2, ax);
        ay = fmaf(unpack_odd(r2),  w2, ay);
        ax = fmaf(unpack_even(r3), w3, ax);
        ay = fmaf(unpack_odd(r3),  w3, ay);
    }
    ax *= dn; ay *= dn;
    uint32 hx = bfbits(ax), hy = bfbits(ay);
    Ah2[i0] = hx | (hy<<16);
    float lx = ax - __uint_as_float(hx<<16);
    float ly = ay - __uint_as_float(hy<<16);
    Al2[i0] = pack2(lx, ly);
}

// ---------------- matmul + bias + BN + ReLU + residual -> packed (Hh,Hl) ----------------

__global__ __launch_bounds__(256)
void k_mm_epi(const __bf16* __restrict__ Ah, const __bf16* __restrict__ Al,
              const __bf16* __restrict__ Bth, const __bf16* __restrict__ Btl,
              const float* __restrict__ bias, const float* __restrict__ gamma,
              const float* __restrict__ beta, uint32* __restrict__ Hh2,
              uint32* __restrict__ Hl2, int residual){
    __shared__ float sT[4][32*36];
    int wave = threadIdx.x >> 6, lane = threadIdx.x & 63;
    int lr = lane & 15, lq = lane >> 4;
    int rbase = blockIdx.x*128 + wave*32;
    const f32x4 zero4 = {0.f,0.f,0.f,0.f};
    size_t o0 = (size_t)(rbase + lr)*H_DIM + lq*8;
    size_t o1 = o0 + (size_t)16*H_DIM;
    bf16x8 A0h[4], A0l[4], A1h[4], A1l[4];
    #pragma unroll
    for(int ks=0;ks<4;ks++){
        A0h[ks] = *(const bf16x8*)(Ah + o0 + ks*32);
        A0l[ks] = *(const bf16x8*)(Al + o0 + ks*32);
        A1h[ks] = *(const bf16x8*)(Ah + o1 + ks*32);
        A1l[ks] = *(const bf16x8*)(Al + o1 + ks*32);
    }
    int orow = lane >> 2;          // 0..15
    int oq   = lane & 3;           // 0..3
    float* sW = sT[wave];
    for(int cp=0; cp<4; cp++){
        #pragma unroll
        for(int cc=0; cc<2; cc++){
            int ct = cp*2 + cc;
            int col = ct*16 + lr;
            f32x4 a0 = zero4, a1 = zero4;
            #pragma unroll
            for(int ks=0;ks<4;ks++){
                bf16x8 Bh = *(const bf16x8*)(Bth + col*H_DIM + ks*32 + lq*8);
                bf16x8 Bl = *(const bf16x8*)(Btl + col*H_DIM + ks*32 + lq*8);
                a0 = __builtin_amdgcn_mfma_f32_16x16x32_bf16(A0h[ks], Bh, a0, 0,0,0);
                a0 = __builtin_amdgcn_mfma_f32_16x16x32_bf16(A0l[ks], Bh, a0, 0,0,0);
                a0 = __builtin_amdgcn_mfma_f32_16x16x32_bf16(A0h[ks], Bl, a0, 0,0,0);
                a1 = __builtin_amdgcn_mfma_f32_16x16x32_bf16(A1h[ks], Bh, a1, 0,0,0);
                a1 = __builtin_amdgcn_mfma_f32_16x16x32_bf16(A1l[ks], Bh, a1, 0,0,0);
                a1 = __builtin_amdgcn_mfma_f32_16x16x32_bf16(A1h[ks], Bl, a1, 0,0,0);
            }
            #pragma unroll
            for(int r=0;r<4;r++){
                sW[(lq*4+r)*36 + cc*16 + lr]    = a0[r];
                sW[(16+lq*4+r)*36 + cc*16 + lr] = a1[r];
            }
        }
        __syncthreads();
        int c0 = cp*32 + oq*8;
        float4 b0 = *(const float4*)(bias + c0);
        float4 b1 = *(const float4*)(bias + c0 + 4);
        float4 g0 = *(const float4*)(gamma + c0);
        float4 g1 = *(const float4*)(gamma + c0 + 4);
        float4 t0 = *(const float4*)(beta + c0);
        float4 t1 = *(const float4*)(beta + c0 + 4);
        float bb[8] = {b0.x,b0.y,b0.z,b0.w,b1.x,b1.y,b1.z,b1.w};
        float gg[8] = {g0.x,g0.y,g0.z,g0.w,g1.x,g1.y,g1.z,g1.w};
        float tt[8] = {t0.x,t0.y,t0.z,t0.w,t1.x,t1.y,t1.z,t1.w};
        #pragma unroll
        for(int g=0; g<2; g++){
            int row = g*16 + orow;
            float v[8];
            *(float4*)&v[0] = *(float4*)&sW[row*36 + oq*8];
            *(float4*)&v[4] = *(float4*)&sW[row*36 + oq*8 + 4];
            size_t oidx = (size_t)(rbase + row)*64 + (c0>>1);
            uint4 oldh, oldl;
            if(residual){
                oldh = *(const uint4*)(Hh2 + oidx);
                oldl = *(const uint4*)(Hl2 + oidx);
            }
            uint32 oh[4], ol[4];
            uint32 ohv[4] = {oldh.x,oldh.y,oldh.z,oldh.w};
            uint32 olv[4] = {oldl.x,oldl.y,oldl.z,oldl.w};
            #pragma unroll
            for(int p=0;p<4;p++){
                float ve = fmaxf(fmaf(v[2*p]   + bb[2*p],   gg[2*p],   tt[2*p]),   0.f);
                float vo = fmaxf(fmaf(v[2*p+1] + bb[2*p+1], gg[2*p+1], tt[2*p+1]), 0.f);
                if(residual){
                    ve += unpack_even(ohv[p]) + unpack_even(olv[p]);
                    vo += unpack_odd(ohv[p])  + unpack_odd(olv[p]);
                }
                uint32 he = bfbits(ve), ho = bfbits(vo);
                oh[p] = he | (ho<<16);
                float le = ve - __uint_as_float(he<<16);
                float lo = vo - __uint_as_float(ho<<16);
                ol[p] = pack2(le, lo);
            }
            *(uint4*)(Hh2 + oidx) = make_uint4(oh[0],oh[1],oh[2],oh[3]);
            *(uint4*)(Hl2 + oidx) = make_uint4(ol[0],ol[1],ol[2],ol[3]);
        }
        __syncthreads();
    }
}

// ---------------- gene GEMM via MFMA, split-K partials (no atomics) ----------------

__global__ __launch_bounds__(256)
void k_gemm_gf_mfma(const __bf16* __restrict__ Ah, const __bf16* __restrict__ Al,
                    const __bf16* __restrict__ Bth, const __bf16* __restrict__ Btl,
                    float* __restrict__ gpart){
    int rt = blockIdx.x & 31;       // 32 row tiles of 64
    int sp = blockIdx.x >> 5;       // 8 k-splits
    int ks0 = (sp*138) >> 3, ks1 = ((sp+1)*138) >> 3;
    int wave = threadIdx.x >> 6, lane = threadIdx.x & 63;
    int lr = lane & 15, lq = lane >> 4;
    int rbase = rt*64 + (wave & 1)*32;
    int cbase = (wave >> 1)*128;
    const f32x4 zero4 = {0.f,0.f,0.f,0.f};
    f32x4 acc[8][2];
    #pragma unroll
    for(int ct=0;ct<8;ct++){ acc[ct][0] = zero4; acc[ct][1] = zero4; }
    for(int ks=ks0; ks<ks1; ks++){
        int kc = ks*32;
        size_t oa0 = (size_t)(rbase + lr)*GF_PAD + kc + lq*8;
        size_t oa1 = oa0 + (size_t)16*GF_PAD;
        bf16x8 A0h = *(const bf16x8*)(Ah + oa0);
        bf16x8 A0l = *(const bf16x8*)(Al + oa0);
        bf16x8 A1h = *(const bf16x8*)(Ah + oa1);
        bf16x8 A1l = *(const bf16x8*)(Al + oa1);
        #pragma unroll
        for(int ct=0;ct<8;ct++){
            size_t bo = (size_t)(cbase + ct*16 + lr)*GF_PAD + kc + lq*8;
            bf16x8 Bh = *(const bf16x8*)(Bth + bo);
            bf16x8 Bl = *(const bf16x8*)(Btl + bo);
            acc[ct][0] = __builtin_amdgcn_mfma_f32_16x16x32_bf16(A0h, Bh, acc[ct][0], 0,0,0);
            acc[ct][0] = __builtin_amdgcn_mfma_f32_16x16x32_bf16(A0l, Bh, acc[ct][0], 0,0,0);
            acc[ct][0] = __builtin_amdgcn_mfma_f32_16x16x32_bf16(A0h, Bl, acc[ct][0], 0,0,0);
            acc[ct][1] = __builtin_amdgcn_mfma_f32_16x16x32_bf16(A1h, Bh, acc[ct][1], 0,0,0);
            acc[ct][1] = __builtin_amdgcn_mfma_f32_16x16x32_bf16(A1l, Bh, acc[ct][1], 0,0,0);
            acc[ct][1] = __builtin_amdgcn_mfma_f32_16x16x32_bf16(A1h, Bl, acc[ct][1], 0,0,0);
        }
    }
    float* po = gpart + (size_t)sp*(B_GR*256);
    #pragma unroll
    for(int ct=0;ct<8;ct++)
        #pragma unroll
        for(int s=0;s<2;s++)
            #pragma unroll
            for(int r=0;r<4;r++)
                po[(size_t)(rbase + s*16 + lq*4 + r)*256 + cbase + ct*16 + lr] = acc[ct][s][r];
}

__global__ void k_gene_reduce(const float* __restrict__ gpart, const float* __restrict__ bias,
                              const float* __restrict__ gamma, const float* __restrict__ beta,
                              float* __restrict__ g1){
    int i = blockIdx.x*256 + threadIdx.x;   // B*256
    int c = i & 255;
    float v = bias[c];
    #pragma unroll
    for(int sp=0;sp<8;sp++) v += gpart[(size_t)sp*(B_GR*256) + i];
    v = fmaf(v, gamma[c]*BN_SCALE, beta[c]);
    g1[i] = fmaxf(v, 0.f);
}

// ---------------- pooling ----------------

__global__ void k_pool(const __bf16* __restrict__ Hh, const __bf16* __restrict__ Hl,
                       float* __restrict__ pool){
    int g = blockIdx.x, c = threadIdx.x;   // 128 threads
    const __bf16* bh = Hh + (size_t)g*64*H_DIM;
    const __bf16* bl = Hl + (size_t)g*64*H_DIM;
    float s = 0.f, m = -3.4e38f;
    for(int i=0;i<64;i++){
        float v = (float)bh[i*H_DIM + c] + (float)bl[i*H_DIM + c];
        s += v; m = fmaxf(m, v);
    }
    pool[g*256 + c]       = s * (1.f/64.f);
    pool[g*256 + 128 + c] = m;
}

// ---------------- small dense layers: LDS-staged A, 4 rows/block ----------------

__global__ void k_dense(const float* __restrict__ A, int ldA, const float* __restrict__ W,
                        const float* __restrict__ bias, const float* __restrict__ gamma,
                        const float* __restrict__ beta, float* __restrict__ out, int ldOut,
                        int K, int logK, int NC, int relu){
    extern __shared__ float sA[];   // 4*K floats
    int rowBase = blockIdx.x*4;
    int c = threadIdx.x;
    for(int idx=threadIdx.x; idx<4*K; idx+=NC){
        int r = idx >> logK, k = idx & (K-1);
        sA[idx] = A[(rowBase+r)*ldA + k];
    }
    __syncthreads();
    float bb = bias[c];
    float acc0=bb, acc1=bb, acc2=bb, acc3=bb;
    for(int k=0;k<K;k++){
        float w = W[k*NC + c];
        acc0 = fmaf(sA[k],     w, acc0);
        acc1 = fmaf(sA[K+k],   w, acc1);
        acc2 = fmaf(sA[2*K+k], w, acc2);
        acc3 = fmaf(sA[3*K+k], w, acc3);
    }
    float gsc = 1.f, bsh = 0.f;
    if(gamma){ gsc = gamma[c]*BN_SCALE; bsh = beta[c]; }
    float v0=acc0, v1=acc1, v2=acc2, v3=acc3;
    if(gamma){ v0=fmaf(v0,gsc,bsh); v1=fmaf(v1,gsc,bsh); v2=fmaf(v2,gsc,bsh); v3=fmaf(v3,gsc,bsh); }
    if(relu){ v0=fmaxf(v0,0.f); v1=fmaxf(v1,0.f); v2=fmaxf(v2,0.f); v3=fmaxf(v3,0.f); }
    out[(rowBase+0)*ldOut + c] = v0;
    out[(rowBase+1)*ldOut + c] = v1;
    out[(rowBase+2)*ldOut + c] = v2;
    out[(rowBase+3)*ldOut + c] = v3;
}

// ---------------- final [2048,64] @ [64,1]: shuffle-reduced ----------------

__global__ void k_final(const float* __restrict__ z2, const float* __restrict__ Wh3,
                        const float* __restrict__ bh3, float* __restrict__ out){
    int lane = threadIdx.x & 63, wr = threadIdx.x >> 6;
    int r = blockIdx.x*4 + wr;
    float v = z2[r*64 + lane] * Wh3[lane];
    #pragma unroll
    for(int off=32; off; off>>=1) v += __shfl_down(v, off);
    if(lane == 0) out[r] = v + bh3[0];
}

// ---------------- launch ----------------

extern "C" void kernel_launch(void* const* d_in, const int* in_sizes, int n_in,
                              void* d_out, int out_size, void* d_ws, size_t ws_size,
                              hipStream_t stream){
    (void)in_sizes; (void)n_in; (void)out_size; (void)ws_size;
    const float* x    = (const float*)d_in[0];
    const float* gf   = (const float*)d_in[1];
    const int*   ei   = (const int*)  d_in[2];
    const float* W_emb= (const float*)d_in[4];
    const float* b_emb= (const float*)d_in[5];
    const float* Wg   = (const float*)d_in[6];
    const float* bg   = (const float*)d_in[7];
    const float* bn_g = (const float*)d_in[8];
    const float* bn_b = (const float*)d_in[9];
    const float* Wd1  = (const float*)d_in[10];
    const float* bd1  = (const float*)d_in[11];
    const float* Wd2  = (const float*)d_in[12];
    const float* bd2  = (const float*)d_in[13];
    const float* Wge1 = (const float*)d_in[14];
    const float* bge1 = (const float*)d_in[15];
    const float* g_g  = (const float*)d_in[16];
    const float* g_b  = (const float*)d_in[17];
    const float* Wge2 = (const float*)d_in[18];
    const float* bge2 = (const float*)d_in[19];
    const float* Wh1  = (const float*)d_in[20];
    const float* bh1  = (const float*)d_in[21];
    const float* h_g  = (const float*)d_in[22];
    const float* h_b  = (const float*)d_in[23];
    const float* Wh2  = (const float*)d_in[24];
    const float* bh2  = (const float*)d_in[25];
    const float* Wh3  = (const float*)d_in[26];
    const float* bh3  = (const float*)d_in[27];
    float* outp = (float*)d_out;

    char* base = (char*)d_ws;
    __bf16* Hh = (__bf16*)base;                              // 32 MiB
    __bf16* Hl = (__bf16*)(base + (32u<<20));                // 32 MiB
    char*   R  = base + (64u<<20);                           // 64 MiB multi-use
    // gene phase (in R):
    __bf16* gfh    = (__bf16*)R;                             // 18,087,936 B
    __bf16* gfl    = (__bf16*)(R + 18087936);
    float*  gpart  = (float*) (R + 36175872);                // 16,777,216 B
    __bf16* wge_th = (__bf16*)(R + 52953088);                // 2,260,992 B
    __bf16* wge_tl = (__bf16*)(R + 55214080);                // end < 64 MiB
    // embedding phase (in R):
    __bf16* xsh = (__bf16*)R;                                // 8 MiB
    __bf16* xsl = (__bf16*)(R + (8u<<20));
    // GCN layer phase (in R):
    __bf16* Ah = (__bf16*)R;                                 // 32 MiB
    __bf16* Al = (__bf16*)(R + (32u<<20));
    // tail:
    char* T = base + (128u<<20);
    float* pool = (float*)T;
    float* g1   = pool + B_GR*256;
    float* t1   = g1   + B_GR*256;
    float* comb = t1   + B_GR*128;
    float* z    = comb + B_GR*256;
    float* z2   = z    + B_GR*128;
    int* rowptr = (int*)(z2 + B_GR*64);
    int* cursor = rowptr + (N_NODES+1);
    int* csr    = cursor + N_NODES;
    int* bsums  = csr + E_EDGES;
    float* dinv = (float*)(bsums + 128);
    __bf16* wg_th = (__bf16*)(dinv + N_NODES);               // 3*16384
    __bf16* wg_tl = wg_th + 3*16384;
    __bf16* we_th = wg_tl + 3*16384;                         // 128*32
    __bf16* we_tl = we_th + 128*32;

    const int* src = ei;
    const int* dst = ei + E_EDGES;

    // graph prep
    k_zero_int   <<<N_NODES/256, 256, 0, stream>>>(cursor, N_NODES);
    k_count      <<<E_EDGES/256, 256, 0, stream>>>(dst, cursor);
    k_scan1      <<<128, 1024, 0, stream>>>(cursor, bsums);
    k_scan2      <<<1, 128, 0, stream>>>(bsums);
    k_scan3      <<<128, 1024, 0, stream>>>(cursor, bsums, rowptr);
    k_dinv_cursor<<<N_NODES/256, 256, 0, stream>>>(rowptr, dinv, cursor);
    k_fill       <<<E_EDGES/256, 256, 0, stream>>>(src, dst, cursor, csr);

    // gene branch
    k_split_gf    <<<(B_GR*GF_PAD)/256, 256, 0, stream>>>(gf, gfh, gfl);
    k_split_wge1  <<<(256*GF_PAD)/256, 256, 0, stream>>>(Wge1, wge_th, wge_tl);
    k_gemm_gf_mfma<<<256, 256, 0, stream>>>(gfh, gfl, wge_th, wge_tl, gpart);
    k_gene_reduce <<<(B_GR*256)/256, 256, 0, stream>>>(gpart, bge1, g_g, g_b, g1);

    // embedding
    k_split_x    <<<(N_NODES*32)/256, 256, 0, stream>>>(x, xsh, xsl);
    k_split_wemb <<<(128*32)/256, 256, 0, stream>>>(W_emb, we_th, we_tl);
    k_split_wg   <<<(3*16384)/256, 256, 0, stream>>>(Wg, wg_th, wg_tl);
    k_emb_mfma   <<<N_NODES/128, 256, 0, stream>>>(xsh, xsl, we_th, we_tl, b_emb,
                                                   (uint32*)Hh, (uint32*)Hl);

    // 3 GCN layers: aggregate-then-matmul (linearity), fused epilogue
    for(int i=0;i<3;i++){
        k_agg   <<<N_NODES/4, 256, 0, stream>>>(Hh, Hl, dinv, rowptr, csr,
                                                (uint32*)Ah, (uint32*)Al);
        k_mm_epi<<<N_NODES/128, 256, 0, stream>>>(Ah, Al, wg_th + i*16384, wg_tl + i*16384,
                                                  bg + i*H_DIM, bn_g + i*H_DIM, bn_b + i*H_DIM,
                                                  (uint32*)Hh, (uint32*)Hl, i > 0);
    }

    // pooling + heads
    k_pool<<<B_GR, 128, 0, stream>>>(Hh, Hl, pool);
    k_dense<<<B_GR/4, 128, 4*256*4, stream>>>(pool, 256, Wd1, bd1, nullptr, nullptr, t1,   128, 256, 8, 128, 1);
    k_dense<<<B_GR/4, 128, 4*128*4, stream>>>(t1,   128, Wd2, bd2, nullptr, nullptr, comb, 256, 128, 7, 128, 0);
    k_dense<<<B_GR/4, 128, 4*256*4, stream>>>(g1,   256, Wge2, bge2, nullptr, nullptr, comb+128, 256, 256, 8, 128, 1);
    k_dense<<<B_GR/4, 128, 4*256*4, stream>>>(comb, 256, Wh1, bh1, h_g, h_b, z, 128, 256, 8, 128, 1);
    k_dense<<<B_GR/4, 64,  4*128*4, stream>>>(z,    128, Wh2, bh2, nullptr, nullptr, z2, 64, 128, 7, 64, 1);
    k_final<<<B_GR/4, 256, 0, stream>>>(z2, Wh3, bh3, outp);
}

// Round 6
// 689.144 us; speedup vs baseline: 1.8620x; 1.0531x over previous
//
#include <hip/hip_runtime.h>

#define N_NODES 131072
#define E_EDGES 524288
#define B_GR    2048
#define H_DIM   128
#define NF_DIM  30
#define GF_DIM  4415
#define GF_PAD  4416            // 138*32
#define BN_SCALE 0.9999950000374997f   // 1/sqrt(1+1e-5)

typedef __bf16 bf16x8 __attribute__((ext_vector_type(8)));
typedef float  f32x4  __attribute__((ext_vector_type(4)));
typedef unsigned int uint32;

__device__ __forceinline__ void split2(float x, __bf16& hi, __bf16& lo){
    hi = (__bf16)x;
    lo = (__bf16)(x - (float)hi);
}
__device__ __forceinline__ uint32 bfbits(float x){
    __bf16 h = (__bf16)x;
    return (uint32)__builtin_bit_cast(unsigned short, h);
}
// packed uint32: low 16 bits = even col, high 16 bits = odd col
__device__ __forceinline__ float unpack_even(uint32 u){ return __uint_as_float(u<<16); }
__device__ __forceinline__ float unpack_odd (uint32 u){ return __uint_as_float(u & 0xffff0000u); }
__device__ __forceinline__ uint32 pack2(float e, float o){ return bfbits(e) | (bfbits(o)<<16); }

// ---------------- graph prep ----------------

__global__ void k_zero_int(int* __restrict__ p, int n){
    int i = blockIdx.x*256 + threadIdx.x;
    if(i < n) p[i] = 0;
}

__global__ void k_count(const int* __restrict__ dst, int* __restrict__ counts){
    int e = blockIdx.x*256 + threadIdx.x;
    if(e < E_EDGES) atomicAdd(&counts[dst[e]], 1);
}

__global__ void k_scan1(int* __restrict__ counts, int* __restrict__ bsums){
    __shared__ int s[1024];
    int t = threadIdx.x;
    int gi = blockIdx.x*1024 + t;
    int v = counts[gi];
    s[t] = v; __syncthreads();
    for(int off=1; off<1024; off<<=1){
        int x = (t>=off) ? s[t-off] : 0;
        __syncthreads();
        s[t] += x;
        __syncthreads();
    }
    counts[gi] = s[t] - v;
    if(t == 1023) bsums[blockIdx.x] = s[t];
}

__global__ void k_scan2(int* __restrict__ bsums){
    __shared__ int s[128];
    int t = threadIdx.x;
    int v = bsums[t]; s[t] = v; __syncthreads();
    for(int off=1; off<128; off<<=1){
        int x = (t>=off) ? s[t-off] : 0;
        __syncthreads();
        s[t] += x;
        __syncthreads();
    }
    bsums[t] = s[t] - v;
}

__global__ void k_scan3(const int* __restrict__ counts, const int* __restrict__ bsums,
                        int* __restrict__ rowptr){
    int i = blockIdx.x*1024 + threadIdx.x;
    rowptr[i] = counts[i] + bsums[blockIdx.x];
    if(i == 0) rowptr[N_NODES] = E_EDGES;
}

__global__ void k_dinv_cursor(const int* __restrict__ rowptr, float* __restrict__ dinv,
                              int* __restrict__ cursor){
    int n = blockIdx.x*256 + threadIdx.x;
    if(n < N_NODES){
        int a = rowptr[n], b = rowptr[n+1];
        dinv[n] = rsqrtf((float)(b - a) + 1.0f);
        cursor[n] = a;
    }
}

__global__ void k_fill(const int* __restrict__ src, const int* __restrict__ dst,
                       int* __restrict__ cursor, int* __restrict__ csr){
    int e = blockIdx.x*256 + threadIdx.x;
    if(e < E_EDGES){
        int p = atomicAdd(&cursor[dst[e]], 1);
        csr[p] = src[e];
    }
}

// ---------------- split-conversion kernels ----------------

__global__ void k_split_x(const float* __restrict__ x, __bf16* __restrict__ xh,
                          __bf16* __restrict__ xl){
    int idx = blockIdx.x*256 + threadIdx.x;          // N*32
    int n = idx >> 5, k = idx & 31;
    float v = (k < NF_DIM) ? x[n*NF_DIM + k] : 0.f;
    split2(v, xh[idx], xl[idx]);
}

__global__ void k_split_wemb(const float* __restrict__ W, __bf16* __restrict__ th,
                             __bf16* __restrict__ tl){
    int idx = blockIdx.x*256 + threadIdx.x;          // 128*32  (c-major, k padded)
    int c = idx >> 5, k = idx & 31;
    float v = (k < NF_DIM) ? W[k*H_DIM + c] : 0.f;
    split2(v, th[idx], tl[idx]);
}

__global__ void k_split_wg(const float* __restrict__ Wg, __bf16* __restrict__ th,
                           __bf16* __restrict__ tl){
    int idx = blockIdx.x*256 + threadIdx.x;          // 3*128*128
    int l = idx >> 14, i = idx & 16383;
    int k = i >> 7, c = i & 127;
    float v = Wg[idx];
    int o = (l << 14) + (c << 7) + k;                // transposed: [l][c][k]
    split2(v, th[o], tl[o]);
}

__global__ void k_split_gf(const float* __restrict__ gf, __bf16* __restrict__ ah,
                           __bf16* __restrict__ al){
    unsigned idx = blockIdx.x*256 + threadIdx.x;     // 2048*4416
    unsigned r = idx / GF_PAD, k = idx - r*GF_PAD;
    float v = (k < GF_DIM) ? gf[(size_t)r*GF_DIM + k] : 0.f;
    split2(v, ah[idx], al[idx]);
}

__global__ void k_split_wge1(const float* __restrict__ W, __bf16* __restrict__ th,
                             __bf16* __restrict__ tl){
    unsigned idx = blockIdx.x*256 + threadIdx.x;     // 256*4416 (c-major, k padded)
    unsigned c = idx / GF_PAD, k = idx - c*GF_PAD;
    float v = (k < GF_DIM) ? W[(size_t)k*256 + c] : 0.f;
    split2(v, th[idx], tl[idx]);
}

// ---------------- embedding via MFMA:  relu(x @ W_emb + b) -> packed (Hh,Hl) ----------------
// epilogue: 64-col phases, full 128-B line writes per row

__global__ __launch_bounds__(256)
void k_emb_mfma(const __bf16* __restrict__ xh, const __bf16* __restrict__ xl,
                const __bf16* __restrict__ wth, const __bf16* __restrict__ wtl,
                const float* __restrict__ bias, uint32* __restrict__ Hh2,
                uint32* __restrict__ Hl2){
    __shared__ float sT[4][32*68];
    int wave = threadIdx.x >> 6, lane = threadIdx.x & 63;
    int lr = lane & 15, lq = lane >> 4;
    int rbase = blockIdx.x*128 + wave*32;
    const f32x4 zero4 = {0.f,0.f,0.f,0.f};
    bf16x8 A0h = *(const bf16x8*)(xh + (size_t)(rbase + lr)*32 + lq*8);
    bf16x8 A0l = *(const bf16x8*)(xl + (size_t)(rbase + lr)*32 + lq*8);
    bf16x8 A1h = *(const bf16x8*)(xh + (size_t)(rbase + 16 + lr)*32 + lq*8);
    bf16x8 A1l = *(const bf16x8*)(xl + (size_t)(rbase + 16 + lr)*32 + lq*8);
    int orow = lane >> 3;          // 0..7
    int oq   = lane & 7;           // 0..7
    float* sW = sT[wave];
    for(int ph=0; ph<2; ph++){
        #pragma unroll
        for(int cc=0; cc<4; cc++){
            int col = (ph*4+cc)*16 + lr;
            bf16x8 Bh = *(const bf16x8*)(wth + col*32 + lq*8);
            bf16x8 Bl = *(const bf16x8*)(wtl + col*32 + lq*8);
            f32x4 a0 = zero4, a1 = zero4;
            a0 = __builtin_amdgcn_mfma_f32_16x16x32_bf16(A0h, Bh, a0, 0,0,0);
            a0 = __builtin_amdgcn_mfma_f32_16x16x32_bf16(A0l, Bh, a0, 0,0,0);
            a0 = __builtin_amdgcn_mfma_f32_16x16x32_bf16(A0h, Bl, a0, 0,0,0);
            a1 = __builtin_amdgcn_mfma_f32_16x16x32_bf16(A1h, Bh, a1, 0,0,0);
            a1 = __builtin_amdgcn_mfma_f32_16x16x32_bf16(A1l, Bh, a1, 0,0,0);
            a1 = __builtin_amdgcn_mfma_f32_16x16x32_bf16(A1h, Bl, a1, 0,0,0);
            #pragma unroll
            for(int r=0;r<4;r++){
                sW[(lq*4+r)*68 + cc*16 + lr]    = a0[r];
                sW[(16+lq*4+r)*68 + cc*16 + lr] = a1[r];
            }
        }
        __syncthreads();
        int cg = ph*64 + oq*8;
        float bb[8];
        *(float4*)&bb[0] = *(const float4*)(bias + cg);
        *(float4*)&bb[4] = *(const float4*)(bias + cg + 4);
        #pragma unroll
        for(int i=0;i<4;i++){
            int row = i*8 + orow;
            float v[8];
            *(float4*)&v[0] = *(float4*)&sW[row*68 + oq*8];
            *(float4*)&v[4] = *(float4*)&sW[row*68 + oq*8 + 4];
            uint32 oh[4], ol[4];
            #pragma unroll
            for(int p=0;p<4;p++){
                float ve = fmaxf(v[2*p]   + bb[2*p],   0.f);
                float vo = fmaxf(v[2*p+1] + bb[2*p+1], 0.f);
                uint32 he = bfbits(ve), ho = bfbits(vo);
                oh[p] = he | (ho<<16);
                float le = ve - __uint_as_float(he<<16);
                float lo = vo - __uint_as_float(ho<<16);
                ol[p] = pack2(le, lo);
            }
            size_t oidx = (size_t)(rbase + row)*64 + (cg>>1);
            *(uint4*)(Hh2 + oidx) = make_uint4(oh[0],oh[1],oh[2],oh[3]);
            *(uint4*)(Hl2 + oidx) = make_uint4(ol[0],ol[1],ol[2],ol[3]);
        }
        __syncthreads();
    }
}

// ---------------- normalized aggregation on H (before matmul), 8-wide gather ----------------

__global__ __launch_bounds__(256)
void k_agg(const __bf16* __restrict__ Hh, const __bf16* __restrict__ Hl,
           const float* __restrict__ dinv, const int* __restrict__ rowptr,
           const int* __restrict__ csr, uint32* __restrict__ Ah2,
           uint32* __restrict__ Al2){
    int wave = threadIdx.x >> 6, lane = threadIdx.x & 63;
    int n = blockIdx.x*4 + wave;
    float dn = dinv[n];
    size_t i0 = (size_t)n*64 + lane;        // uint32 units (2 bf16 per uint)
    const uint32* Hh2 = (const uint32*)Hh;
    const uint32* Hl2 = (const uint32*)Hl;
    uint32 sh = Hh2[i0], sl = Hl2[i0];
    float sx = unpack_even(sh) + unpack_even(sl);
    float sy = unpack_odd(sh)  + unpack_odd(sl);
    float ax = sx*dn, ay = sy*dn;
    int j0 = rowptr[n], j1 = rowptr[n+1];
    int jm = j1 - 1;
    for(int j=j0; j<j1; j+=8){
        int jj[8]; float ww[8]; uint32 rr[8];
        #pragma unroll
        for(int t=0;t<8;t++){
            int idx = (j+t<=jm) ? j+t : jm;
            jj[t] = csr[idx];
        }
        #pragma unroll
        for(int t=0;t<8;t++){
            ww[t] = (j+t<=jm) ? dinv[jj[t]] : 0.f;
            rr[t] = Hh2[(size_t)jj[t]*64 + lane];
        }
        #pragma unroll
        for(int t=0;t<8;t++){
            ax = fmaf(unpack_even(rr[t]), ww[t], ax);
            ay = fmaf(unpack_odd(rr[t]),  ww[t], ay);
        }
    }
    ax *= dn; ay *= dn;
    uint32 hx = bfbits(ax), hy = bfbits(ay);
    Ah2[i0] = hx | (hy<<16);
    float lx = ax - __uint_as_float(hx<<16);
    float ly = ay - __uint_as_float(hy<<16);
    Al2[i0] = pack2(lx, ly);
}

// ---------------- matmul + bias + BN + ReLU + residual -> packed (Hh,Hl) ----------------
// epilogue: 64-col phases, full 128-B line writes per row

__global__ __launch_bounds__(256)
void k_mm_epi(const __bf16* __restrict__ Ah, const __bf16* __restrict__ Al,
              const __bf16* __restrict__ Bth, const __bf16* __restrict__ Btl,
              const float* __restrict__ bias, const float* __restrict__ gamma,
              const float* __restrict__ beta, uint32* __restrict__ Hh2,
              uint32* __restrict__ Hl2, int residual){
    __shared__ float sT[4][32*68];
    int wave = threadIdx.x >> 6, lane = threadIdx.x & 63;
    int lr = lane & 15, lq = lane >> 4;
    int rbase = blockIdx.x*128 + wave*32;
    const f32x4 zero4 = {0.f,0.f,0.f,0.f};
    size_t o0 = (size_t)(rbase + lr)*H_DIM + lq*8;
    size_t o1 = o0 + (size_t)16*H_DIM;
    bf16x8 A0h[4], A0l[4], A1h[4], A1l[4];
    #pragma unroll
    for(int ks=0;ks<4;ks++){
        A0h[ks] = *(const bf16x8*)(Ah + o0 + ks*32);
        A0l[ks] = *(const bf16x8*)(Al + o0 + ks*32);
        A1h[ks] = *(const bf16x8*)(Ah + o1 + ks*32);
        A1l[ks] = *(const bf16x8*)(Al + o1 + ks*32);
    }
    int orow = lane >> 3;          // 0..7
    int oq   = lane & 7;           // 0..7
    float* sW = sT[wave];
    for(int ph=0; ph<2; ph++){
        #pragma unroll
        for(int cc=0; cc<4; cc++){
            int col = (ph*4+cc)*16 + lr;
            f32x4 a0 = zero4, a1 = zero4;
            #pragma unroll
            for(int ks=0;ks<4;ks++){
                bf16x8 Bh = *(const bf16x8*)(Bth + col*H_DIM + ks*32 + lq*8);
                bf16x8 Bl = *(const bf16x8*)(Btl + col*H_DIM + ks*32 + lq*8);
                a0 = __builtin_amdgcn_mfma_f32_16x16x32_bf16(A0h[ks], Bh, a0, 0,0,0);
                a0 = __builtin_amdgcn_mfma_f32_16x16x32_bf16(A0l[ks], Bh, a0, 0,0,0);
                a0 = __builtin_amdgcn_mfma_f32_16x16x32_bf16(A0h[ks], Bl, a0, 0,0,0);
                a1 = __builtin_amdgcn_mfma_f32_16x16x32_bf16(A1h[ks], Bh, a1, 0,0,0);
                a1 = __builtin_amdgcn_mfma_f32_16x16x32_bf16(A1l[ks], Bh, a1, 0,0,0);
                a1 = __builtin_amdgcn_mfma_f32_16x16x32_bf16(A1h[ks], Bl, a1, 0,0,0);
            }
            #pragma unroll
            for(int r=0;r<4;r++){
                sW[(lq*4+r)*68 + cc*16 + lr]    = a0[r];
                sW[(16+lq*4+r)*68 + cc*16 + lr] = a1[r];
            }
        }
        __syncthreads();
        int cg = ph*64 + oq*8;
        float bb[8], gg[8], tt[8];
        *(float4*)&bb[0] = *(const float4*)(bias + cg);
        *(float4*)&bb[4] = *(const float4*)(bias + cg + 4);
        *(float4*)&gg[0] = *(const float4*)(gamma + cg);
        *(float4*)&gg[4] = *(const float4*)(gamma + cg + 4);
        *(float4*)&tt[0] = *(const float4*)(beta + cg);
        *(float4*)&tt[4] = *(const float4*)(beta + cg + 4);
        #pragma unroll
        for(int p=0;p<8;p++) gg[p] *= BN_SCALE;
        #pragma unroll
        for(int i=0;i<4;i++){
            int row = i*8 + orow;
            float v[8];
            *(float4*)&v[0] = *(float4*)&sW[row*68 + oq*8];
            *(float4*)&v[4] = *(float4*)&sW[row*68 + oq*8 + 4];
            size_t oidx = (size_t)(rbase + row)*64 + (cg>>1);
            uint4 oldh = {0,0,0,0}, oldl = {0,0,0,0};
            if(residual){
                oldh = *(const uint4*)(Hh2 + oidx);
                oldl = *(const uint4*)(Hl2 + oidx);
            }
            uint32 ohv[4] = {oldh.x,oldh.y,oldh.z,oldh.w};
            uint32 olv[4] = {oldl.x,oldl.y,oldl.z,oldl.w};
            uint32 oh[4], ol[4];
            #pragma unroll
            for(int p=0;p<4;p++){
                float ve = fmaxf(fmaf(v[2*p]   + bb[2*p],   gg[2*p],   tt[2*p]),   0.f);
                float vo = fmaxf(fmaf(v[2*p+1] + bb[2*p+1], gg[2*p+1], tt[2*p+1]), 0.f);
                if(residual){
                    ve += unpack_even(ohv[p]) + unpack_even(olv[p]);
                    vo += unpack_odd(ohv[p])  + unpack_odd(olv[p]);
                }
                uint32 he = bfbits(ve), ho = bfbits(vo);
                oh[p] = he | (ho<<16);
                float le = ve - __uint_as_float(he<<16);
                float lo = vo - __uint_as_float(ho<<16);
                ol[p] = pack2(le, lo);
            }
            *(uint4*)(Hh2 + oidx) = make_uint4(oh[0],oh[1],oh[2],oh[3]);
            *(uint4*)(Hl2 + oidx) = make_uint4(ol[0],ol[1],ol[2],ol[3]);
        }
        __syncthreads();
    }
}

// ---------------- gene GEMM via MFMA, split-K partials (no atomics) ----------------

__global__ __launch_bounds__(256)
void k_gemm_gf_mfma(const __bf16* __restrict__ Ah, const __bf16* __restrict__ Al,
                    const __bf16* __restrict__ Bth, const __bf16* __restrict__ Btl,
                    float* __restrict__ gpart){
    int rt = blockIdx.x & 31;       // 32 row tiles of 64
    int sp = blockIdx.x >> 5;       // 8 k-splits
    int ks0 = (sp*138) >> 3, ks1 = ((sp+1)*138) >> 3;
    int wave = threadIdx.x >> 6, lane = threadIdx.x & 63;
    int lr = lane & 15, lq = lane >> 4;
    int rbase = rt*64 + (wave & 1)*32;
    int cbase = (wave >> 1)*128;
    const f32x4 zero4 = {0.f,0.f,0.f,0.f};
    f32x4 acc[8][2];
    #pragma unroll
    for(int ct=0;ct<8;ct++){ acc[ct][0] = zero4; acc[ct][1] = zero4; }
    for(int ks=ks0; ks<ks1; ks++){
        int kc = ks*32;
        size_t oa0 = (size_t)(rbase + lr)*GF_PAD + kc + lq*8;
        size_t oa1 = oa0 + (size_t)16*GF_PAD;
        bf16x8 A0h = *(const bf16x8*)(Ah + oa0);
        bf16x8 A0l = *(const bf16x8*)(Al + oa0);
        bf16x8 A1h = *(const bf16x8*)(Ah + oa1);
        bf16x8 A1l = *(const bf16x8*)(Al + oa1);
        #pragma unroll
        for(int ct=0;ct<8;ct++){
            size_t bo = (size_t)(cbase + ct*16 + lr)*GF_PAD + kc + lq*8;
            bf16x8 Bh = *(const bf16x8*)(Bth + bo);
            bf16x8 Bl = *(const bf16x8*)(Btl + bo);
            acc[ct][0] = __builtin_amdgcn_mfma_f32_16x16x32_bf16(A0h, Bh, acc[ct][0], 0,0,0);
            acc[ct][0] = __builtin_amdgcn_mfma_f32_16x16x32_bf16(A0l, Bh, acc[ct][0], 0,0,0);
            acc[ct][0] = __builtin_amdgcn_mfma_f32_16x16x32_bf16(A0h, Bl, acc[ct][0], 0,0,0);
            acc[ct][1] = __builtin_amdgcn_mfma_f32_16x16x32_bf16(A1h, Bh, acc[ct][1], 0,0,0);
            acc[ct][1] = __builtin_amdgcn_mfma_f32_16x16x32_bf16(A1l, Bh, acc[ct][1], 0,0,0);
            acc[ct][1] = __builtin_amdgcn_mfma_f32_16x16x32_bf16(A1h, Bl, acc[ct][1], 0,0,0);
        }
    }
    float* po = gpart + (size_t)sp*(B_GR*256);
    #pragma unroll
    for(int ct=0;ct<8;ct++)
        #pragma unroll
        for(int s=0;s<2;s++)
            #pragma unroll
            for(int r=0;r<4;r++)
                po[(size_t)(rbase + s*16 + lq*4 + r)*256 + cbase + ct*16 + lr] = acc[ct][s][r];
}

__global__ void k_gene_reduce(const float* __restrict__ gpart, const float* __restrict__ bias,
                              const float* __restrict__ gamma, const float* __restrict__ beta,
                              float* __restrict__ g1){
    int i = blockIdx.x*256 + threadIdx.x;   // B*256
    int c = i & 255;
    float v = bias[c];
    #pragma unroll
    for(int sp=0;sp<8;sp++) v += gpart[(size_t)sp*(B_GR*256) + i];
    v = fmaf(v, gamma[c]*BN_SCALE, beta[c]);
    g1[i] = fmaxf(v, 0.f);
}

// ---------------- pooling ----------------

__global__ void k_pool(const __bf16* __restrict__ Hh, const __bf16* __restrict__ Hl,
                       float* __restrict__ pool){
    int g = blockIdx.x, c = threadIdx.x;   // 128 threads
    const __bf16* bh = Hh + (size_t)g*64*H_DIM;
    const __bf16* bl = Hl + (size_t)g*64*H_DIM;
    float s = 0.f, m = -3.4e38f;
    for(int i=0;i<64;i++){
        float v = (float)bh[i*H_DIM + c] + (float)bl[i*H_DIM + c];
        s += v; m = fmaxf(m, v);
    }
    pool[g*256 + c]       = s * (1.f/64.f);
    pool[g*256 + 128 + c] = m;
}

// ---------------- small dense layers: LDS-staged A, 4 rows/block ----------------

__global__ void k_dense(const float* __restrict__ A, int ldA, const float* __restrict__ W,
                        const float* __restrict__ bias, const float* __restrict__ gamma,
                        const float* __restrict__ beta, float* __restrict__ out, int ldOut,
                        int K, int logK, int NC, int relu){
    extern __shared__ float sA[];   // 4*K floats
    int rowBase = blockIdx.x*4;
    int c = threadIdx.x;
    for(int idx=threadIdx.x; idx<4*K; idx+=NC){
        int r = idx >> logK, k = idx & (K-1);
        sA[idx] = A[(rowBase+r)*ldA + k];
    }
    __syncthreads();
    float bb = bias[c];
    float acc0=bb, acc1=bb, acc2=bb, acc3=bb;
    for(int k=0;k<K;k++){
        float w = W[k*NC + c];
        acc0 = fmaf(sA[k],     w, acc0);
        acc1 = fmaf(sA[K+k],   w, acc1);
        acc2 = fmaf(sA[2*K+k], w, acc2);
        acc3 = fmaf(sA[3*K+k], w, acc3);
    }
    float gsc = 1.f, bsh = 0.f;
    if(gamma){ gsc = gamma[c]*BN_SCALE; bsh = beta[c]; }
    float v0=acc0, v1=acc1, v2=acc2, v3=acc3;
    if(gamma){ v0=fmaf(v0,gsc,bsh); v1=fmaf(v1,gsc,bsh); v2=fmaf(v2,gsc,bsh); v3=fmaf(v3,gsc,bsh); }
    if(relu){ v0=fmaxf(v0,0.f); v1=fmaxf(v1,0.f); v2=fmaxf(v2,0.f); v3=fmaxf(v3,0.f); }
    out[(rowBase+0)*ldOut + c] = v0;
    out[(rowBase+1)*ldOut + c] = v1;
    out[(rowBase+2)*ldOut + c] = v2;
    out[(rowBase+3)*ldOut + c] = v3;
}

// ---------------- final [2048,64] @ [64,1]: shuffle-reduced ----------------

__global__ void k_final(const float* __restrict__ z2, const float* __restrict__ Wh3,
                        const float* __restrict__ bh3, float* __restrict__ out){
    int lane = threadIdx.x & 63, wr = threadIdx.x >> 6;
    int r = blockIdx.x*4 + wr;
    float v = z2[r*64 + lane] * Wh3[lane];
    #pragma unroll
    for(int off=32; off; off>>=1) v += __shfl_down(v, off);
    if(lane == 0) out[r] = v + bh3[0];
}

// ---------------- launch ----------------

extern "C" void kernel_launch(void* const* d_in, const int* in_sizes, int n_in,
                              void* d_out, int out_size, void* d_ws, size_t ws_size,
                              hipStream_t stream){
    (void)in_sizes; (void)n_in; (void)out_size; (void)ws_size;
    const float* x    = (const float*)d_in[0];
    const float* gf   = (const float*)d_in[1];
    const int*   ei   = (const int*)  d_in[2];
    const float* W_emb= (const float*)d_in[4];
    const float* b_emb= (const float*)d_in[5];
    const float* Wg   = (const float*)d_in[6];
    const float* bg   = (const float*)d_in[7];
    const float* bn_g = (const float*)d_in[8];
    const float* bn_b = (const float*)d_in[9];
    const float* Wd1  = (const float*)d_in[10];
    const float* bd1  = (const float*)d_in[11];
    const float* Wd2  = (const float*)d_in[12];
    const float* bd2  = (const float*)d_in[13];
    const float* Wge1 = (const float*)d_in[14];
    const float* bge1 = (const float*)d_in[15];
    const float* g_g  = (const float*)d_in[16];
    const float* g_b  = (const float*)d_in[17];
    const float* Wge2 = (const float*)d_in[18];
    const float* bge2 = (const float*)d_in[19];
    const float* Wh1  = (const float*)d_in[20];
    const float* bh1  = (const float*)d_in[21];
    const float* h_g  = (const float*)d_in[22];
    const float* h_b  = (const float*)d_in[23];
    const float* Wh2  = (const float*)d_in[24];
    const float* bh2  = (const float*)d_in[25];
    const float* Wh3  = (const float*)d_in[26];
    const float* bh3  = (const float*)d_in[27];
    float* outp = (float*)d_out;

    char* base = (char*)d_ws;
    __bf16* Hh = (__bf16*)base;                              // 32 MiB
    __bf16* Hl = (__bf16*)(base + (32u<<20));                // 32 MiB
    char*   R  = base + (64u<<20);                           // 64 MiB multi-use
    // gene phase (in R):
    __bf16* gfh    = (__bf16*)R;                             // 18,087,936 B
    __bf16* gfl    = (__bf16*)(R + 18087936);
    float*  gpart  = (float*) (R + 36175872);                // 16,777,216 B
    __bf16* wge_th = (__bf16*)(R + 52953088);                // 2,260,992 B
    __bf16* wge_tl = (__bf16*)(R + 55214080);                // end < 64 MiB
    // embedding phase (in R):
    __bf16* xsh = (__bf16*)R;                                // 8 MiB
    __bf16* xsl = (__bf16*)(R + (8u<<20));
    // GCN layer phase (in R):
    __bf16* Ah = (__bf16*)R;                                 // 32 MiB
    __bf16* Al = (__bf16*)(R + (32u<<20));
    // tail:
    char* T = base + (128u<<20);
    float* pool = (float*)T;
    float* g1   = pool + B_GR*256;
    float* t1   = g1   + B_GR*256;
    float* comb = t1   + B_GR*128;
    float* z    = comb + B_GR*256;
    float* z2   = z    + B_GR*128;
    int* rowptr = (int*)(z2 + B_GR*64);
    int* cursor = rowptr + (N_NODES+1);
    int* csr    = cursor + N_NODES;
    int* bsums  = csr + E_EDGES;
    float* dinv = (float*)(bsums + 128);
    __bf16* wg_th = (__bf16*)(dinv + N_NODES);               // 3*16384
    __bf16* wg_tl = wg_th + 3*16384;
    __bf16* we_th = wg_tl + 3*16384;                         // 128*32
    __bf16* we_tl = we_th + 128*32;

    const int* src = ei;
    const int* dst = ei + E_EDGES;

    // graph prep
    k_zero_int   <<<N_NODES/256, 256, 0, stream>>>(cursor, N_NODES);
    k_count      <<<E_EDGES/256, 256, 0, stream>>>(dst, cursor);
    k_scan1      <<<128, 1024, 0, stream>>>(cursor, bsums);
    k_scan2      <<<1, 128, 0, stream>>>(bsums);
    k_scan3      <<<128, 1024, 0, stream>>>(cursor, bsums, rowptr);
    k_dinv_cursor<<<N_NODES/256, 256, 0, stream>>>(rowptr, dinv, cursor);
    k_fill       <<<E_EDGES/256, 256, 0, stream>>>(src, dst, cursor, csr);

    // gene branch
    k_split_gf    <<<(B_GR*GF_PAD)/256, 256, 0, stream>>>(gf, gfh, gfl);
    k_split_wge1  <<<(256*GF_PAD)/256, 256, 0, stream>>>(Wge1, wge_th, wge_tl);
    k_gemm_gf_mfma<<<256, 256, 0, stream>>>(gfh, gfl, wge_th, wge_tl, gpart);
    k_gene_reduce <<<(B_GR*256)/256, 256, 0, stream>>>(gpart, bge1, g_g, g_b, g1);

    // embedding
    k_split_x    <<<(N_NODES*32)/256, 256, 0, stream>>>(x, xsh, xsl);
    k_split_wemb <<<(128*32)/256, 256, 0, stream>>>(W_emb, we_th, we_tl);
    k_split_wg   <<<(3*16384)/256, 256, 0, stream>>>(Wg, wg_th, wg_tl);
    k_emb_mfma   <<<N_NODES/128, 256, 0, stream>>>(xsh, xsl, we_th, we_tl, b_emb,
                                                   (uint32*)Hh, (uint32*)Hl);

    // 3 GCN layers: aggregate-then-matmul (linearity), fused epilogue
    for(int i=0;i<3;i++){
        k_agg   <<<N_NODES/4, 256, 0, stream>>>(Hh, Hl, dinv, rowptr, csr,
                                                (uint32*)Ah, (uint32*)Al);
        k_mm_epi<<<N_NODES/128, 256, 0, stream>>>(Ah, Al, wg_th + i*16384, wg_tl + i*16384,
                                                  bg + i*H_DIM, bn_g + i*H_DIM, bn_b + i*H_DIM,
                                                  (uint32*)Hh, (uint32*)Hl, i > 0);
    }

    // pooling + heads
    k_pool<<<B_GR, 128, 0, stream>>>(Hh, Hl, pool);
    k_dense<<<B_GR/4, 128, 4*256*4, stream>>>(pool, 256, Wd1, bd1, nullptr, nullptr, t1,   128, 256, 8, 128, 1);
    k_dense<<<B_GR/4, 128, 4*128*4, stream>>>(t1,   128, Wd2, bd2, nullptr, nullptr, comb, 256, 128, 7, 128, 0);
    k_dense<<<B_GR/4, 128, 4*256*4, stream>>>(g1,   256, Wge2, bge2, nullptr, nullptr, comb+128, 256, 256, 8, 128, 1);
    k_dense<<<B_GR/4, 128, 4*256*4, stream>>>(comb, 256, Wh1, bh1, h_g, h_b, z, 128, 256, 8, 128, 1);
    k_dense<<<B_GR/4, 64,  4*128*4, stream>>>(z,    128, Wh2, bh2, nullptr, nullptr, z2, 64, 128, 7, 64, 1);
    k_final<<<B_GR/4, 256, 0, stream>>>(z2, Wh3, bh3, outp);
}